// Round 13
// baseline (1610.737 us; speedup 1.0000x reference)
//
#include <hip/hip_runtime.h>
#include <math.h>

#define NN 15000      // nodes
#define NE 60000      // edges
#define DIN 74
#define DEIN 12
#define DD 64         // node feat dim
#define EH 128        // edge hidden
#define NG 8192       // EH*DD
#define NGX 8256      // NG + 64 (Bh fold)
#define NSTEPS 6
#define NPART 938     // ceil(NN/16)

typedef unsigned short ushort_t;
typedef __attribute__((ext_vector_type(8))) short short8v;
typedef __attribute__((ext_vector_type(4))) float float4v;

__device__ __forceinline__ float bsf(unsigned short u){
  union { unsigned int i; float f; } v; v.i = ((unsigned int)u) << 16; return v.f;
}
__device__ __forceinline__ float blo(unsigned int u){
  union { unsigned int i; float f; } v; v.i = u << 16; return v.f;
}
__device__ __forceinline__ float bhi(unsigned int u){
  union { unsigned int i; float f; } v; v.i = u & 0xffff0000u; return v.f;
}
__device__ __forceinline__ unsigned short fsb(float f){
  union { float f; unsigned int i; } v; v.f = f;
  unsigned int x = v.i;
  return (unsigned short)((x + 0x7FFFu + ((x >> 16) & 1u)) >> 16);
}

// ---------- dtype sniff
__global__ void k_sniff(const ushort_t* __restrict__ nf16,
                        const int* __restrict__ dsti, int* __restrict__ flags){
  __shared__ int cnt[2];
  int t = threadIdx.x;
  if (t < 2) cnt[t] = 0;
  __syncthreads();
  int bad = 0;
  for (int i = t; i < 1024; i += 256){
    unsigned short u = nf16[2*i];
    int e = (u >> 7) & 0xFF;
    if (e < 96 || e > 159) bad++;
  }
  if (bad) atomicAdd(&cnt[0], bad);
  if (t < 256 && dsti[2*t+1] == 0) atomicAdd(&cnt[1], 1);
  __syncthreads();
  if (t == 0){
    flags[0] = (cnt[0] > 300) ? 1 : 0;
    flags[1] = (cnt[1] > 250) ? 1 : 0;
  }
}

// ---------- batched canonicalization: 15 tensors in one dispatch
struct CanonArgs {
  const void* in[15];
  float* out[15];
  int n[15];
};
__global__ void k_canon_all(CanonArgs a, const int* __restrict__ flags){
  int j = blockIdx.y;
  int n = a.n[j];
  int fp32 = flags[0];
  const void* in = a.in[j];
  float* out = a.out[j];
  for (int i = blockIdx.x*256 + threadIdx.x; i < n; i += gridDim.x*256){
    if (fp32) out[i] = ((const float*)in)[i];
    else      out[i] = bsf(((const ushort_t*)in)[i]);
  }
}
__global__ void k_canoni(const void* __restrict__ in, int* __restrict__ out,
                         int n, const int* __restrict__ flags){
  int i = blockIdx.x*256 + threadIdx.x;
  if (i >= n) return;
  long long v = flags[1] ? ((const long long*)in)[i]
                         : (long long)((const int*)in)[i];
  int vi = (int)v;
  if (vi < 0) vi = 0;
  if (vi >= NN) vi = NN-1;
  out[i] = vi;
}

// ---------- one-time: h0 = relu(nf @ W_proj + b_proj) -> fp32 + bf16 shadow
__global__ void k_proj(const float* __restrict__ nf, const float* __restrict__ Wp,
                       const float* __restrict__ bp, float* __restrict__ hid,
                       ushort_t* __restrict__ hidb){
  __shared__ float nfl[4][DIN];
  int t = threadIdx.x, blk = blockIdx.x;
  for (int idx = t; idx < 4*DIN; idx += 256){
    int vl = idx / DIN, i = idx - vl*DIN;
    nfl[vl][i] = nf[(size_t)(blk*4+vl)*DIN + i];
  }
  __syncthreads();
  int vl = t >> 6, o = t & 63;
  int v = blk*4 + vl;
  float acc = bp[o];
  for (int i = 0; i < DIN; ++i) acc += nfl[vl][i] * Wp[i*DD + o];
  float r = fmaxf(acc, 0.f);
  hid[(size_t)v*DD + o] = r;
  hidb[(size_t)v*DD + o] = fsb(r);
}

// ---------- one-time: t = relu(ef @ W_e1 + b_e1), fp32
__global__ void k_emlp(const float* __restrict__ ef, const float* __restrict__ W1,
                       const float* __restrict__ b1, float* __restrict__ tfp){
  __shared__ float efl[2][DEIN];
  int t = threadIdx.x, blk = blockIdx.x;
  if (t < 2*DEIN){
    int el = t / DEIN, i = t - el*DEIN;
    efl[el][i] = ef[(size_t)(blk*2+el)*DEIN + i];
  }
  __syncthreads();
  int el = t >> 7, c = t & 127;
  float acc = b1[c];
  for (int i = 0; i < DEIN; ++i) acc += efl[el][i] * W1[i*EH + c];
  tfp[(size_t)(blk*2+el)*EH + c] = fmaxf(acc, 0.f);
}

// ---------- one-time: w2rtx rows permuted so G comes out o-major
__global__ void k_w2rtx(const float* __restrict__ W2, const float* __restrict__ b2,
                        ushort_t* __restrict__ w2rtx){
  int idx = blockIdx.x*256 + threadIdx.x;
  if (idx < NGX*DD){
    int n = idx >> 6, i = idx & 63;
    float v;
    if (n < NG){
      int o = n >> 7, k = n & 127;
      v = W2[(size_t)k*4096 + i*64 + o];
    } else {
      v = b2[i*64 + (n - NG)];
    }
    w2rtx[idx] = fsb(v);
  }
}

// ---------- CSR build
__global__ void k_zero(int* __restrict__ p, int n){
  int i = blockIdx.x*256 + threadIdx.x;
  if (i < n) p[i] = 0;
}
__global__ void k_deg(const int* __restrict__ idxarr, int* __restrict__ deg){
  int e = blockIdx.x*256 + threadIdx.x;
  if (e < NE) atomicAdd(&deg[idxarr[e]], 1);
}
__global__ void k_scan(const int* __restrict__ deg, int* __restrict__ rowp,
                       float* __restrict__ invd){
  __shared__ int ssum[256];
  int t = threadIdx.x;
  const int STRIP = (NN + 255) / 256;
  int lo = t*STRIP, hi = (lo + STRIP < NN) ? lo + STRIP : NN;
  int s = 0;
  for (int i = lo; i < hi; ++i) s += deg[i];
  ssum[t] = s;
  __syncthreads();
  if (t == 0){
    int acc = 0;
    for (int i = 0; i < 256; ++i){ int v = ssum[i]; ssum[i] = acc; acc += v; }
  }
  __syncthreads();
  int acc = ssum[t];
  for (int i = lo; i < hi; ++i){
    rowp[i] = acc;
    int d = deg[i];
    invd[i] = (d > 0) ? 1.0f/(float)d : 0.0f;
    acc += d;
  }
  if (t == 255) rowp[NN] = acc;
}
__global__ void k_scatter(const int* __restrict__ idxarr, const int* __restrict__ rowp,
                          int* __restrict__ cursor, int* __restrict__ eidx){
  int e = blockIdx.x*256 + threadIdx.x;
  if (e < NE){
    int d = idxarr[e];
    int pos = atomicAdd(&cursor[d], 1);
    eidx[rowp[d] + pos] = e;
  }
}

// ---------- per chunk: G[m][n'] = hidb[chunk0+m] @ w2rtx  (bf16 MFMA)
__global__ __launch_bounds__(256) void k_ggemm(const ushort_t* __restrict__ hidb,
        const ushort_t* __restrict__ w2rtx, ushort_t* __restrict__ G,
        int chunk0, int cact){
  __shared__ __align__(16) ushort_t As[64][72];
  __shared__ __align__(16) ushort_t Bs[64][72];
  int t = threadIdx.x;
  int n0 = blockIdx.x * 64;
  int m0 = blockIdx.y * 64;
  #pragma unroll
  for (int it = 0; it < 2; ++it){
    int cid = t + it*256;
    int r = cid >> 3, ko = (cid & 7) * 8;
    int gm = chunk0 + m0 + r; if (gm >= NN) gm = NN-1;   // clamp; store guarded
    *(uint4*)&As[r][ko] = *(const uint4*)(hidb + (size_t)gm*DD + ko);
    *(uint4*)&Bs[r][ko] = *(const uint4*)(w2rtx + (size_t)(n0 + r)*DD + ko);
  }
  __syncthreads();
  int w = t >> 6, lane = t & 63;
  int lrow = lane & 15, quad = lane >> 4;
  float4v acc[4];
  #pragma unroll
  for (int nt = 0; nt < 4; ++nt) acc[nt] = (float4v){0.f,0.f,0.f,0.f};
  #pragma unroll
  for (int ks = 0; ks < 2; ++ks){
    short8v a = *(const short8v*)&As[w*16 + lrow][ks*32 + quad*8];
    #pragma unroll
    for (int nt = 0; nt < 4; ++nt){
      short8v b = *(const short8v*)&Bs[nt*16 + lrow][ks*32 + quad*8];
      acc[nt] = __builtin_amdgcn_mfma_f32_16x16x32_bf16(a, b, acc[nt], 0, 0, 0);
    }
  }
  #pragma unroll
  for (int nt = 0; nt < 4; ++nt){
    int col = n0 + nt*16 + lrow;
    #pragma unroll
    for (int reg = 0; reg < 4; ++reg){
      int m = m0 + w*16 + quad*4 + reg;
      if (m < cact) G[(size_t)m*NGX + col] = fsb(acc[nt][reg]);
    }
  }
}

// ---------- per chunk: msg[e,o] = sum_k t[e,k]*G[src][o*128+k] + G[src][8192+o]
__global__ __launch_bounds__(256) void k_edge(const float* __restrict__ tfp,
      const ushort_t* __restrict__ G,
      const int* __restrict__ rowp2, const int* __restrict__ eidx2,
      float* __restrict__ msg, int chunk0){
  __shared__ __align__(16) ushort_t gl[NG];    // 16 KB, swizzled per-o chunks
  __shared__ __align__(16) ushort_t bhl[64];
  __shared__ __align__(16) float tl[4][128];   // 2 KB
  __shared__ int eids[4];
  int t = threadIdx.x;
  int vloc = blockIdx.x;
  int v = chunk0 + vloc;
  int b = rowp2[v], e_end = rowp2[v+1];
  if (b == e_end) return;                      // block-uniform
  const ushort_t* grow = G + (size_t)vloc*NGX;
  for (int idx = t; idx < 1032; idx += 256){   // 1032 uint4 = 8256 bf16, coalesced
    uint4 val = *(const uint4*)(grow + idx*8);
    if (idx < 1024){
      int o = idx >> 4, c = idx & 15;
      *(uint4*)&gl[o*128 + ((c ^ (o & 15)) << 3)] = val;
    } else {
      *(uint4*)&bhl[(idx - 1024)*8] = val;
    }
  }
  int w = t >> 6, o = t & 63;
  int sw = o & 15;
  const uint4* gv = (const uint4*)&gl[o*128];  // 16 swizzled chunks of 8 bf16
  for (int base = b; base < e_end; base += 4){
    __syncthreads();                           // also covers gl/bhl visibility
    if (t < 4){
      int ei = base + t;
      eids[t] = (ei < e_end) ? eidx2[ei] : -1;
    }
    __syncthreads();
    for (int idx = t; idx < 512; idx += 256){
      int slot = idx >> 7, k = idx & 127;
      int e = eids[slot];
      tl[slot][k] = (e >= 0) ? tfp[(size_t)e*EH + k] : 0.f;
    }
    __syncthreads();
    int e = eids[w];
    if (e >= 0){
      float acc = bsf(bhl[o]);
      #pragma unroll
      for (int c = 0; c < 16; ++c){
        uint4 g8 = gv[c ^ sw];
        float4 ta = *(const float4*)&tl[w][c*8];
        float4 tb = *(const float4*)&tl[w][c*8 + 4];
        acc += ta.x*blo(g8.x) + ta.y*bhi(g8.x) + ta.z*blo(g8.y) + ta.w*bhi(g8.y);
        acc += tb.x*blo(g8.z) + tb.y*bhi(g8.z) + tb.z*blo(g8.w) + tb.w*bhi(g8.w);
      }
      msg[(size_t)e*DD + o] = acc;
    }
  }
}

// ---------- per step: rst = mean msg + bias; fused BN column partials
__global__ __launch_bounds__(256) void k_aggrbn(const float* __restrict__ msg,
      const int* __restrict__ rowp, const int* __restrict__ eidx,
      const float* __restrict__ invd, const float* __restrict__ cbias,
      float* __restrict__ rst, float* __restrict__ part){
  __shared__ float ls[4][64], ls2[4][64];
  int t = threadIdx.x, blk = blockIdx.x;
  int o = t & 63, w = t >> 6;
  float cb = cbias[o];
  float s = 0.f, s2 = 0.f;
  #pragma unroll
  for (int j = 0; j < 4; ++j){
    int v = blk*16 + w*4 + j;
    if (v < NN){
      float acc = 0.f;
      int b = rowp[v], e2 = rowp[v+1];
      for (int idx = b; idx < e2; ++idx)
        acc += msg[(size_t)eidx[idx]*DD + o];
      float r = acc*invd[v] + cb;
      rst[(size_t)v*DD + o] = r;
      s += r; s2 += r*r;
    }
  }
  ls[w][o] = s; ls2[w][o] = s2;
  __syncthreads();
  if (w == 0){
    part[blk*128 + o]      = ls[0][o]+ls[1][o]+ls[2][o]+ls[3][o];
    part[blk*128 + 64 + o] = ls2[0][o]+ls2[1][o]+ls2[2][o]+ls2[3][o];
  }
}
__global__ void k_bnf(const float* __restrict__ part, float* __restrict__ stats){
  __shared__ float sh[128];
  int t = threadIdx.x;  // 128 threads
  float s = 0.f;
  for (int b = 0; b < NPART; ++b) s += part[b*128 + t];
  sh[t] = s;
  __syncthreads();
  if (t < 64){
    float mu = sh[t] / (float)NN;
    float var = sh[64+t] / (float)NN - mu*mu;
    if (var < 0.f) var = 0.f;
    stats[t] = mu;
    stats[64 + t] = rsqrtf(var + 1e-5f);
  }
}

// ---------- per step: GRU, 16 nodes/block, LDS-transposed weight tiles
// (round-10 version verbatim — measured 50 µs, VGPR 68, no spill)
__global__ __launch_bounds__(256) void k_gru(const float* __restrict__ rst,
      const float* __restrict__ stats,
      const float* __restrict__ gamma, const float* __restrict__ beta,
      const float* __restrict__ Wih, const float* __restrict__ Whh,
      const float* __restrict__ bih, const float* __restrict__ bhh,
      float* __restrict__ hid, ushort_t* __restrict__ hidb,
      float* __restrict__ out, int write_out){
  __shared__ float ml[16][65], hl[16][65];
  __shared__ float wtI[64][65], wtH[64][65];
  int t = threadIdx.x, blk = blockIdx.x;
  int o = t & 63, w = t >> 6;
  float st_mu = stats[o], st_rs = stats[64+o], ga = gamma[o], be = beta[o];
  #pragma unroll
  for (int j = 0; j < 4; ++j){
    int n = w*4 + j;
    int v = blk*16 + n;
    float x  = (v < NN) ? rst[(size_t)v*DD + o] : 0.f;
    float hp = (v < NN) ? hid[(size_t)v*DD + o] : 0.f;
    ml[n][o] = fmaxf((x - st_mu)*st_rs*ga + be, 0.f);
    hl[n][o] = hp;
  }
  float accI[3][4], accH[3][4];
  #pragma unroll
  for (int g = 0; g < 3; ++g){
    float bi = bih[g*64+o], bh = bhh[g*64+o];
    #pragma unroll
    for (int j = 0; j < 4; ++j){ accI[g][j] = bi; accH[g][j] = bh; }
  }
  #pragma unroll
  for (int g = 0; g < 3; ++g){
    __syncthreads();
    for (int idx = t; idx < 4096; idx += 256){
      int row = idx >> 6, i = idx & 63;       // row = gate-output index
      wtI[i][row] = Wih[(size_t)(g*64+row)*64 + i];
      wtH[i][row] = Whh[(size_t)(g*64+row)*64 + i];
    }
    __syncthreads();
    for (int i = 0; i < 64; ++i){
      float wi = wtI[i][o], wh = wtH[i][o];
      #pragma unroll
      for (int j = 0; j < 4; ++j){
        int n = w*4 + j;
        accI[g][j] += ml[n][i]*wi;
        accH[g][j] += hl[n][i]*wh;
      }
    }
  }
  #pragma unroll
  for (int j = 0; j < 4; ++j){
    int n = w*4 + j;
    int v = blk*16 + n;
    if (v < NN){
      float r  = 1.f/(1.f+__expf(-(accI[0][j]+accH[0][j])));
      float z  = 1.f/(1.f+__expf(-(accI[1][j]+accH[1][j])));
      float nn_= tanhf(accI[2][j] + r*accH[2][j]);
      float hnew = (1.f - z)*nn_ + z*hl[n][o];
      hid[(size_t)v*DD + o] = hnew;
      hidb[(size_t)v*DD + o] = fsb(hnew);
      if (write_out) out[(size_t)v*DD + o] = hnew;
    }
  }
}

extern "C" void kernel_launch(void* const* d_in, const int* in_sizes, int n_in,
                              void* d_out, int out_size, void* d_ws, size_t ws_size,
                              hipStream_t stream){
  (void)out_size;
  float* out = (float*)d_out;

  // resolve input positions by size (== dict order on this instance)
  int p_nf=-1,p_ef=-1,p_src=-1,p_dst=-1,p_Wp=-1,p_bp=-1,p_W1=-1,p_b1=-1,
      p_W2=-1,p_b2=-1,p_cb=-1,p_gam=-1,p_bet=-1,p_Wih=-1,p_Whh=-1,p_bih=-1,p_bhh=-1;
  int c60000=0,c64=0,c12288=0,c192=0;
  for (int i = 0; i < n_in; ++i){
    switch (in_sizes[i]){
      case 1110000: p_nf = i; break;
      case 720000:  p_ef = i; break;
      case 60000:   if (c60000++ == 0) p_src = i; else p_dst = i; break;
      case 4736:    p_Wp = i; break;
      case 64:      { if (c64==0) p_bp=i; else if (c64==1) p_cb=i;
                      else if (c64==2) p_gam=i; else p_bet=i; c64++; } break;
      case 1536:    p_W1 = i; break;
      case 128:     p_b1 = i; break;
      case 524288:  p_W2 = i; break;
      case 4096:    p_b2 = i; break;
      case 12288:   if (c12288++ == 0) p_Wih = i; else p_Whh = i; break;
      case 192:     if (c192++ == 0) p_bih = i; else p_bhh = i; break;
      default: break;
    }
  }

  char* p = (char*)d_ws;
  auto alloc = [&](size_t bytes)->char*{
    char* r = p; p += (bytes + 255) & ~(size_t)255; return r;
  };
  int* flags = (int*)alloc(256);
  const int FPOS[15] = {p_nf,p_ef,p_Wp,p_bp,p_W1,p_b1,p_W2,p_b2,p_cb,p_gam,p_bet,
                        p_Wih,p_Whh,p_bih,p_bhh};
  CanonArgs ca;
  int maxn = 0;
  for (int j = 0; j < 15; ++j){
    int n = in_sizes[FPOS[j]];
    ca.in[j]  = d_in[FPOS[j]];
    ca.out[j] = (float*)alloc((size_t)n * 4);
    ca.n[j]   = n;
    if (n > maxn) maxn = n;
  }
  const float* nf  = ca.out[0];  const float* ef  = ca.out[1];
  const float* Wp  = ca.out[2];  const float* bp  = ca.out[3];
  const float* W1  = ca.out[4];  const float* b1  = ca.out[5];
  const float* W2  = ca.out[6];  const float* b2  = ca.out[7];
  const float* cb  = ca.out[8];  const float* gam = ca.out[9];
  const float* bet = ca.out[10]; const float* Wih = ca.out[11];
  const float* Whh = ca.out[12]; const float* bih = ca.out[13];
  const float* bhh = ca.out[14];
  int* srcc = (int*)alloc((size_t)NE*4);
  int* dstc = (int*)alloc((size_t)NE*4);

  float* tfp      = (float*)alloc((size_t)NE*EH*4);     // 30.7 MB
  ushort_t* w2rtx = (ushort_t*)alloc((size_t)NGX*DD*2); // 1.06 MB
  float* hid      = (float*)alloc((size_t)NN*DD*4);
  ushort_t* hidb  = (ushort_t*)alloc((size_t)NN*DD*2);
  float* msg      = (float*)alloc((size_t)NE*DD*4);     // 15.4 MB
  float* rst      = (float*)alloc((size_t)NN*DD*4);
  float* part     = (float*)alloc((size_t)NPART*128*4);
  float* stats    = (float*)alloc(128*4);
  int* degall     = (int*)alloc((size_t)4*NN*4);
  int* deg  = degall;        int* cursor  = degall + NN;
  int* deg2 = degall + 2*NN; int* cursor2 = degall + 3*NN;
  int* rowp   = (int*)alloc((size_t)(NN+1)*4);
  float* invd = (float*)alloc((size_t)NN*4);
  int* eidx   = (int*)alloc((size_t)NE*4);
  int* rowp2  = (int*)alloc((size_t)(NN+1)*4);
  float* invd2= (float*)alloc((size_t)NN*4);
  int* eidx2  = (int*)alloc((size_t)NE*4);

  // adaptive bf16 G-chunk (deterministic per ws_size)
  // cap at 7520 rows (~124 MB): G buffer + tfp + msg stay L3-resident (256 MB),
  // so the G write->read round-trip never touches HBM (round-12 lesson: C=15040
  // = 248 MB spilled G to HBM and made k_ggemm/k_edge HBM-bound).
  size_t used = (size_t)(p - (char*)d_ws);
  size_t rem = (ws_size > used) ? (ws_size - used) : 0;
  long long Cll = (long long)(rem / ((size_t)NGX*2));
  int C = (Cll > 7520) ? 7520 : (int)Cll;
  C &= ~63;
  if (C < 64)  C = 64;
  ushort_t* G = (ushort_t*)alloc((size_t)C*NGX*2);
  int nch = (NN + C - 1) / C;

  k_sniff<<<1, 256, 0, stream>>>((const ushort_t*)d_in[p_nf], (const int*)d_in[p_dst], flags);
  k_canon_all<<<dim3((maxn+255)/256, 15), 256, 0, stream>>>(ca, flags);
  k_canoni<<<(NE+255)/256, 256, 0, stream>>>(d_in[p_src], srcc, NE, flags);
  k_canoni<<<(NE+255)/256, 256, 0, stream>>>(d_in[p_dst], dstc, NE, flags);

  k_proj <<<NN/4,  256, 0, stream>>>(nf, Wp, bp, hid, hidb);
  k_emlp <<<NE/2,  256, 0, stream>>>(ef, W1, b1, tfp);
  k_w2rtx<<<(NGX*DD+255)/256, 256, 0, stream>>>(W2, b2, w2rtx);
  k_zero <<<(4*NN+255)/256, 256, 0, stream>>>(degall, 4*NN);
  k_deg  <<<(NE+255)/256, 256, 0, stream>>>(dstc, deg);
  k_deg  <<<(NE+255)/256, 256, 0, stream>>>(srcc, deg2);
  k_scan <<<1, 256, 0, stream>>>(deg, rowp, invd);
  k_scan <<<1, 256, 0, stream>>>(deg2, rowp2, invd2);
  k_scatter<<<(NE+255)/256, 256, 0, stream>>>(dstc, rowp, cursor, eidx);
  k_scatter<<<(NE+255)/256, 256, 0, stream>>>(srcc, rowp2, cursor2, eidx2);

  for (int s = 0; s < NSTEPS; ++s){
    for (int c = 0; c < nch; ++c){
      int chunk0 = c*C;
      int cact = (NN - chunk0 < C) ? (NN - chunk0) : C;
      k_ggemm<<<dim3(NGX/64, (cact+63)/64), 256, 0, stream>>>(hidb, w2rtx, G, chunk0, cact);
      k_edge <<<cact, 256, 0, stream>>>(tfp, G, rowp2, eidx2, msg, chunk0);
    }
    k_aggrbn<<<NPART, 256, 0, stream>>>(msg, rowp, eidx, invd, cb, rst, part);
    k_bnf   <<<1, 128, 0, stream>>>(part, stats);
    k_gru   <<<NPART, 256, 0, stream>>>(rst, stats, gam, bet, Wih, Whh, bih, bhh,
                                        hid, hidb, out, (s == NSTEPS-1) ? 1 : 0);
  }
}

// Round 14
// 1489.055 us; speedup vs baseline: 1.0817x; 1.0817x over previous
//
#include <hip/hip_runtime.h>
#include <math.h>

#define NN 15000      // nodes
#define NE 60000      // edges
#define DIN 74
#define DEIN 12
#define DD 64         // node feat dim
#define EH 128        // edge hidden
#define NG 8192       // EH*DD
#define NGX 8256      // NG + 64 (Bh fold)
#define NSTEPS 6
#define NPART 938     // ceil(NN/16)  (aggrbn)
#define NPARTG 469    // ceil(NN/32)  (gru)

typedef unsigned short ushort_t;
typedef __attribute__((ext_vector_type(8))) short short8v;
typedef __attribute__((ext_vector_type(4))) float float4v;

__device__ __forceinline__ float bsf(unsigned short u){
  union { unsigned int i; float f; } v; v.i = ((unsigned int)u) << 16; return v.f;
}
__device__ __forceinline__ float blo(unsigned int u){
  union { unsigned int i; float f; } v; v.i = u << 16; return v.f;
}
__device__ __forceinline__ float bhi(unsigned int u){
  union { unsigned int i; float f; } v; v.i = u & 0xffff0000u; return v.f;
}
__device__ __forceinline__ unsigned short fsb(float f){
  union { float f; unsigned int i; } v; v.f = f;
  unsigned int x = v.i;
  return (unsigned short)((x + 0x7FFFu + ((x >> 16) & 1u)) >> 16);
}

// ---------- dtype sniff
__global__ void k_sniff(const ushort_t* __restrict__ nf16,
                        const int* __restrict__ dsti, int* __restrict__ flags){
  __shared__ int cnt[2];
  int t = threadIdx.x;
  if (t < 2) cnt[t] = 0;
  __syncthreads();
  int bad = 0;
  for (int i = t; i < 1024; i += 256){
    unsigned short u = nf16[2*i];
    int e = (u >> 7) & 0xFF;
    if (e < 96 || e > 159) bad++;
  }
  if (bad) atomicAdd(&cnt[0], bad);
  if (t < 256 && dsti[2*t+1] == 0) atomicAdd(&cnt[1], 1);
  __syncthreads();
  if (t == 0){
    flags[0] = (cnt[0] > 300) ? 1 : 0;
    flags[1] = (cnt[1] > 250) ? 1 : 0;
  }
}

// ---------- batched canonicalization: 15 tensors in one dispatch
struct CanonArgs {
  const void* in[15];
  float* out[15];
  int n[15];
};
__global__ void k_canon_all(CanonArgs a, const int* __restrict__ flags){
  int j = blockIdx.y;
  int n = a.n[j];
  int fp32 = flags[0];
  const void* in = a.in[j];
  float* out = a.out[j];
  for (int i = blockIdx.x*256 + threadIdx.x; i < n; i += gridDim.x*256){
    if (fp32) out[i] = ((const float*)in)[i];
    else      out[i] = bsf(((const ushort_t*)in)[i]);
  }
}
__global__ void k_canoni(const void* __restrict__ in, int* __restrict__ out,
                         int n, const int* __restrict__ flags){
  int i = blockIdx.x*256 + threadIdx.x;
  if (i >= n) return;
  long long v = flags[1] ? ((const long long*)in)[i]
                         : (long long)((const int*)in)[i];
  int vi = (int)v;
  if (vi < 0) vi = 0;
  if (vi >= NN) vi = NN-1;
  out[i] = vi;
}

// ---------- one-time: h0 = relu(nf @ W_proj + b_proj) -> fp32 + bf16 shadow
__global__ void k_proj(const float* __restrict__ nf, const float* __restrict__ Wp,
                       const float* __restrict__ bp, float* __restrict__ hid,
                       ushort_t* __restrict__ hidb){
  __shared__ float nfl[4][DIN];
  int t = threadIdx.x, blk = blockIdx.x;
  for (int idx = t; idx < 4*DIN; idx += 256){
    int vl = idx / DIN, i = idx - vl*DIN;
    nfl[vl][i] = nf[(size_t)(blk*4+vl)*DIN + i];
  }
  __syncthreads();
  int vl = t >> 6, o = t & 63;
  int v = blk*4 + vl;
  float acc = bp[o];
  for (int i = 0; i < DIN; ++i) acc += nfl[vl][i] * Wp[i*DD + o];
  float r = fmaxf(acc, 0.f);
  hid[(size_t)v*DD + o] = r;
  hidb[(size_t)v*DD + o] = fsb(r);
}

// ---------- one-time: t = relu(ef @ W_e1 + b_e1), fp32
__global__ void k_emlp(const float* __restrict__ ef, const float* __restrict__ W1,
                       const float* __restrict__ b1, float* __restrict__ tfp){
  __shared__ float efl[2][DEIN];
  int t = threadIdx.x, blk = blockIdx.x;
  if (t < 2*DEIN){
    int el = t / DEIN, i = t - el*DEIN;
    efl[el][i] = ef[(size_t)(blk*2+el)*DEIN + i];
  }
  __syncthreads();
  int el = t >> 7, c = t & 127;
  float acc = b1[c];
  for (int i = 0; i < DEIN; ++i) acc += efl[el][i] * W1[i*EH + c];
  tfp[(size_t)(blk*2+el)*EH + c] = fmaxf(acc, 0.f);
}

// ---------- one-time: w2rtx rows permuted so G comes out o-major
__global__ void k_w2rtx(const float* __restrict__ W2, const float* __restrict__ b2,
                        ushort_t* __restrict__ w2rtx){
  int idx = blockIdx.x*256 + threadIdx.x;
  if (idx < NGX*DD){
    int n = idx >> 6, i = idx & 63;
    float v;
    if (n < NG){
      int o = n >> 7, k = n & 127;
      v = W2[(size_t)k*4096 + i*64 + o];
    } else {
      v = b2[i*64 + (n - NG)];
    }
    w2rtx[idx] = fsb(v);
  }
}

// ---------- CSR build
__global__ void k_zero(int* __restrict__ p, int n){
  int i = blockIdx.x*256 + threadIdx.x;
  if (i < n) p[i] = 0;
}
__global__ void k_deg(const int* __restrict__ idxarr, int* __restrict__ deg){
  int e = blockIdx.x*256 + threadIdx.x;
  if (e < NE) atomicAdd(&deg[idxarr[e]], 1);
}
__global__ void k_scan(const int* __restrict__ deg, int* __restrict__ rowp,
                       float* __restrict__ invd){
  __shared__ int ssum[256];
  int t = threadIdx.x;
  const int STRIP = (NN + 255) / 256;
  int lo = t*STRIP, hi = (lo + STRIP < NN) ? lo + STRIP : NN;
  int s = 0;
  for (int i = lo; i < hi; ++i) s += deg[i];
  ssum[t] = s;
  __syncthreads();
  if (t == 0){
    int acc = 0;
    for (int i = 0; i < 256; ++i){ int v = ssum[i]; ssum[i] = acc; acc += v; }
  }
  __syncthreads();
  int acc = ssum[t];
  for (int i = lo; i < hi; ++i){
    rowp[i] = acc;
    int d = deg[i];
    invd[i] = (d > 0) ? 1.0f/(float)d : 0.0f;
    acc += d;
  }
  if (t == 255) rowp[NN] = acc;
}
__global__ void k_scatter(const int* __restrict__ idxarr, const int* __restrict__ rowp,
                          int* __restrict__ cursor, int* __restrict__ eidx){
  int e = blockIdx.x*256 + threadIdx.x;
  if (e < NE){
    int d = idxarr[e];
    int pos = atomicAdd(&cursor[d], 1);
    eidx[rowp[d] + pos] = e;
  }
}

// ---------- per chunk: G[m][n'] = hidb[chunk0+m] @ w2rtx  (bf16 MFMA, 128x64 tile)
__global__ __launch_bounds__(256) void k_ggemm(const ushort_t* __restrict__ hidb,
        const ushort_t* __restrict__ w2rtx, ushort_t* __restrict__ G,
        int chunk0, int cact){
  __shared__ __align__(16) ushort_t As[128][72];  // 18.4 KB
  __shared__ __align__(16) ushort_t Bs[64][72];   //  9.2 KB
  int t = threadIdx.x;
  int n0 = blockIdx.x * 64;
  int m0 = blockIdx.y * 128;
  #pragma unroll
  for (int it = 0; it < 6; ++it){
    int cid = t + it*256;
    int r = cid >> 3, ko = (cid & 7) * 8;
    if (r < 128){
      int gm = chunk0 + m0 + r; if (gm >= NN) gm = NN-1;  // clamp; store guarded
      *(uint4*)&As[r][ko] = *(const uint4*)(hidb + (size_t)gm*DD + ko);
    } else {
      *(uint4*)&Bs[r-128][ko] = *(const uint4*)(w2rtx + (size_t)(n0 + r-128)*DD + ko);
    }
  }
  __syncthreads();
  int w = t >> 6, lane = t & 63;
  int lrow = lane & 15, quad = lane >> 4;
  float4v acc[2][4];
  #pragma unroll
  for (int mt = 0; mt < 2; ++mt)
    #pragma unroll
    for (int nt = 0; nt < 4; ++nt) acc[mt][nt] = (float4v){0.f,0.f,0.f,0.f};
  #pragma unroll
  for (int ks = 0; ks < 2; ++ks){
    short8v a0 = *(const short8v*)&As[w*32 + lrow][ks*32 + quad*8];
    short8v a1 = *(const short8v*)&As[w*32 + 16 + lrow][ks*32 + quad*8];
    #pragma unroll
    for (int nt = 0; nt < 4; ++nt){
      short8v b = *(const short8v*)&Bs[nt*16 + lrow][ks*32 + quad*8];
      acc[0][nt] = __builtin_amdgcn_mfma_f32_16x16x32_bf16(a0, b, acc[0][nt], 0, 0, 0);
      acc[1][nt] = __builtin_amdgcn_mfma_f32_16x16x32_bf16(a1, b, acc[1][nt], 0, 0, 0);
    }
  }
  #pragma unroll
  for (int mt = 0; mt < 2; ++mt){
    #pragma unroll
    for (int nt = 0; nt < 4; ++nt){
      int col = n0 + nt*16 + lrow;
      #pragma unroll
      for (int reg = 0; reg < 4; ++reg){
        int m = m0 + w*32 + mt*16 + quad*4 + reg;
        if (m < cact) G[(size_t)m*NGX + col] = fsb(acc[mt][nt][reg]);
      }
    }
  }
}

// ---------- per chunk: msg[e,o] = sum_k t[e,k]*G[src][o*128+k] + G[src][8192+o]
__global__ __launch_bounds__(256) void k_edge(const float* __restrict__ tfp,
      const ushort_t* __restrict__ G,
      const int* __restrict__ rowp2, const int* __restrict__ eidx2,
      float* __restrict__ msg, int chunk0){
  __shared__ __align__(16) ushort_t gl[NG];    // 16 KB, swizzled per-o chunks
  __shared__ __align__(16) ushort_t bhl[64];
  __shared__ __align__(16) float tl[4][128];   // 2 KB
  __shared__ int eids[4];
  int t = threadIdx.x;
  int vloc = blockIdx.x;
  int v = chunk0 + vloc;
  int b = rowp2[v], e_end = rowp2[v+1];
  if (b == e_end) return;                      // block-uniform
  const ushort_t* grow = G + (size_t)vloc*NGX;
  for (int idx = t; idx < 1032; idx += 256){   // 1032 uint4 = 8256 bf16, coalesced
    uint4 val = *(const uint4*)(grow + idx*8);
    if (idx < 1024){
      int o = idx >> 4, c = idx & 15;
      *(uint4*)&gl[o*128 + ((c ^ (o & 15)) << 3)] = val;
    } else {
      *(uint4*)&bhl[(idx - 1024)*8] = val;
    }
  }
  int w = t >> 6, o = t & 63;
  int sw = o & 15;
  const uint4* gv = (const uint4*)&gl[o*128];  // 16 swizzled chunks of 8 bf16
  for (int base = b; base < e_end; base += 4){
    __syncthreads();                           // also covers gl/bhl visibility
    if (t < 4){
      int ei = base + t;
      eids[t] = (ei < e_end) ? eidx2[ei] : -1;
    }
    __syncthreads();
    for (int idx = t; idx < 512; idx += 256){
      int slot = idx >> 7, k = idx & 127;
      int e = eids[slot];
      tl[slot][k] = (e >= 0) ? tfp[(size_t)e*EH + k] : 0.f;
    }
    __syncthreads();
    int e = eids[w];
    if (e >= 0){
      float acc = bsf(bhl[o]);
      #pragma unroll
      for (int c = 0; c < 16; ++c){
        uint4 g8 = gv[c ^ sw];
        float4 ta = *(const float4*)&tl[w][c*8];
        float4 tb = *(const float4*)&tl[w][c*8 + 4];
        acc += ta.x*blo(g8.x) + ta.y*bhi(g8.x) + ta.z*blo(g8.y) + ta.w*bhi(g8.y);
        acc += tb.x*blo(g8.z) + tb.y*bhi(g8.z) + tb.z*blo(g8.w) + tb.w*bhi(g8.w);
      }
      msg[(size_t)e*DD + o] = acc;
    }
  }
}

// ---------- per step: rst = mean msg + bias; fused BN column partials
__global__ __launch_bounds__(256) void k_aggrbn(const float* __restrict__ msg,
      const int* __restrict__ rowp, const int* __restrict__ eidx,
      const float* __restrict__ invd, const float* __restrict__ cbias,
      float* __restrict__ rst, float* __restrict__ part){
  __shared__ float ls[4][64], ls2[4][64];
  int t = threadIdx.x, blk = blockIdx.x;
  int o = t & 63, w = t >> 6;
  float cb = cbias[o];
  float s = 0.f, s2 = 0.f;
  #pragma unroll
  for (int j = 0; j < 4; ++j){
    int v = blk*16 + w*4 + j;
    if (v < NN){
      float acc = 0.f;
      int b = rowp[v], e2 = rowp[v+1];
      for (int idx = b; idx < e2; ++idx)
        acc += msg[(size_t)eidx[idx]*DD + o];
      float r = acc*invd[v] + cb;
      rst[(size_t)v*DD + o] = r;
      s += r; s2 += r*r;
    }
  }
  ls[w][o] = s; ls2[w][o] = s2;
  __syncthreads();
  if (w == 0){
    part[blk*128 + o]      = ls[0][o]+ls[1][o]+ls[2][o]+ls[3][o];
    part[blk*128 + 64 + o] = ls2[0][o]+ls2[1][o]+ls2[2][o]+ls2[3][o];
  }
}
__global__ void k_bnf(const float* __restrict__ part, float* __restrict__ stats){
  __shared__ float sh[128];
  int t = threadIdx.x;  // 128 threads
  float s = 0.f;
  for (int b = 0; b < NPART; ++b) s += part[b*128 + t];
  sh[t] = s;
  __syncthreads();
  if (t < 64){
    float mu = sh[t] / (float)NN;
    float var = sh[64+t] / (float)NN - mu*mu;
    if (var < 0.f) var = 0.f;
    stats[t] = mu;
    stats[64 + t] = rsqrtf(var + 1e-5f);
  }
}

// ---------- per step: GRU, 32 nodes/block, sum-folded r/z accumulators
// r,z gates only need gi+gh -> accumulate the sum directly (4 accs/node not 6)
__global__ __launch_bounds__(256) void k_gru(const float* __restrict__ rst,
      const float* __restrict__ stats,
      const float* __restrict__ gamma, const float* __restrict__ beta,
      const float* __restrict__ Wih, const float* __restrict__ Whh,
      const float* __restrict__ bih, const float* __restrict__ bhh,
      float* __restrict__ hid, ushort_t* __restrict__ hidb,
      float* __restrict__ out, int write_out){
  __shared__ float ml[32][65], hl[32][65];     // 16.6 KB
  __shared__ float wtI[64][65], wtH[64][65];   // 33.3 KB
  int t = threadIdx.x, blk = blockIdx.x;
  int o = t & 63, w = t >> 6;
  float st_mu = stats[o], st_rs = stats[64+o], ga = gamma[o], be = beta[o];
  #pragma unroll
  for (int j = 0; j < 8; ++j){
    int n = w*8 + j;
    int v = blk*32 + n;
    float x  = (v < NN) ? rst[(size_t)v*DD + o] : 0.f;
    float hp = (v < NN) ? hid[(size_t)v*DD + o] : 0.f;
    ml[n][o] = fmaxf((x - st_mu)*st_rs*ga + be, 0.f);
    hl[n][o] = hp;
  }
  float aR[8], aZ[8], aNi[8], aNh[8];
  {
    float bR = bih[o] + bhh[o];
    float bZ = bih[64+o] + bhh[64+o];
    float bNi = bih[128+o], bNh = bhh[128+o];
    #pragma unroll
    for (int j = 0; j < 8; ++j){ aR[j]=bR; aZ[j]=bZ; aNi[j]=bNi; aNh[j]=bNh; }
  }
  #pragma unroll
  for (int g = 0; g < 3; ++g){
    __syncthreads();
    for (int idx = t; idx < 4096; idx += 256){
      int row = idx >> 6, i = idx & 63;       // row = gate-output index
      wtI[i][row] = Wih[(size_t)(g*64+row)*64 + i];
      wtH[i][row] = Whh[(size_t)(g*64+row)*64 + i];
    }
    __syncthreads();
    for (int i = 0; i < 64; ++i){
      float wi = wtI[i][o], wh = wtH[i][o];
      #pragma unroll
      for (int j = 0; j < 8; ++j){
        int n = w*8 + j;
        float mv = ml[n][i], hv = hl[n][i];
        if (g == 0)      aR[j]  += mv*wi + hv*wh;
        else if (g == 1) aZ[j]  += mv*wi + hv*wh;
        else           { aNi[j] += mv*wi; aNh[j] += hv*wh; }
      }
    }
  }
  #pragma unroll
  for (int j = 0; j < 8; ++j){
    int n = w*8 + j;
    int v = blk*32 + n;
    if (v < NN){
      float r  = 1.f/(1.f+__expf(-aR[j]));
      float z  = 1.f/(1.f+__expf(-aZ[j]));
      float nn_= tanhf(aNi[j] + r*aNh[j]);
      float hnew = (1.f - z)*nn_ + z*hl[n][o];
      hid[(size_t)v*DD + o] = hnew;
      hidb[(size_t)v*DD + o] = fsb(hnew);
      if (write_out) out[(size_t)v*DD + o] = hnew;
    }
  }
}

extern "C" void kernel_launch(void* const* d_in, const int* in_sizes, int n_in,
                              void* d_out, int out_size, void* d_ws, size_t ws_size,
                              hipStream_t stream){
  (void)out_size;
  float* out = (float*)d_out;

  // resolve input positions by size (== dict order on this instance)
  int p_nf=-1,p_ef=-1,p_src=-1,p_dst=-1,p_Wp=-1,p_bp=-1,p_W1=-1,p_b1=-1,
      p_W2=-1,p_b2=-1,p_cb=-1,p_gam=-1,p_bet=-1,p_Wih=-1,p_Whh=-1,p_bih=-1,p_bhh=-1;
  int c60000=0,c64=0,c12288=0,c192=0;
  for (int i = 0; i < n_in; ++i){
    switch (in_sizes[i]){
      case 1110000: p_nf = i; break;
      case 720000:  p_ef = i; break;
      case 60000:   if (c60000++ == 0) p_src = i; else p_dst = i; break;
      case 4736:    p_Wp = i; break;
      case 64:      { if (c64==0) p_bp=i; else if (c64==1) p_cb=i;
                      else if (c64==2) p_gam=i; else p_bet=i; c64++; } break;
      case 1536:    p_W1 = i; break;
      case 128:     p_b1 = i; break;
      case 524288:  p_W2 = i; break;
      case 4096:    p_b2 = i; break;
      case 12288:   if (c12288++ == 0) p_Wih = i; else p_Whh = i; break;
      case 192:     if (c192++ == 0) p_bih = i; else p_bhh = i; break;
      default: break;
    }
  }

  char* p = (char*)d_ws;
  auto alloc = [&](size_t bytes)->char*{
    char* r = p; p += (bytes + 255) & ~(size_t)255; return r;
  };
  int* flags = (int*)alloc(256);
  const int FPOS[15] = {p_nf,p_ef,p_Wp,p_bp,p_W1,p_b1,p_W2,p_b2,p_cb,p_gam,p_bet,
                        p_Wih,p_Whh,p_bih,p_bhh};
  CanonArgs ca;
  int maxn = 0;
  for (int j = 0; j < 15; ++j){
    int n = in_sizes[FPOS[j]];
    ca.in[j]  = d_in[FPOS[j]];
    ca.out[j] = (float*)alloc((size_t)n * 4);
    ca.n[j]   = n;
    if (n > maxn) maxn = n;
  }
  const float* nf  = ca.out[0];  const float* ef  = ca.out[1];
  const float* Wp  = ca.out[2];  const float* bp  = ca.out[3];
  const float* W1  = ca.out[4];  const float* b1  = ca.out[5];
  const float* W2  = ca.out[6];  const float* b2  = ca.out[7];
  const float* cb  = ca.out[8];  const float* gam = ca.out[9];
  const float* bet = ca.out[10]; const float* Wih = ca.out[11];
  const float* Whh = ca.out[12]; const float* bih = ca.out[13];
  const float* bhh = ca.out[14];
  int* srcc = (int*)alloc((size_t)NE*4);
  int* dstc = (int*)alloc((size_t)NE*4);

  float* tfp      = (float*)alloc((size_t)NE*EH*4);     // 30.7 MB
  ushort_t* w2rtx = (ushort_t*)alloc((size_t)NGX*DD*2); // 1.06 MB
  float* hid      = (float*)alloc((size_t)NN*DD*4);
  ushort_t* hidb  = (ushort_t*)alloc((size_t)NN*DD*2);
  float* msg      = (float*)alloc((size_t)NE*DD*4);     // 15.4 MB
  float* rst      = (float*)alloc((size_t)NN*DD*4);
  float* part     = (float*)alloc((size_t)NPART*128*4);
  float* stats    = (float*)alloc(128*4);
  int* degall     = (int*)alloc((size_t)4*NN*4);
  int* deg  = degall;        int* cursor  = degall + NN;
  int* deg2 = degall + 2*NN; int* cursor2 = degall + 3*NN;
  int* rowp   = (int*)alloc((size_t)(NN+1)*4);
  float* invd = (float*)alloc((size_t)NN*4);
  int* eidx   = (int*)alloc((size_t)NE*4);
  int* rowp2  = (int*)alloc((size_t)(NN+1)*4);
  float* invd2= (float*)alloc((size_t)NN*4);
  int* eidx2  = (int*)alloc((size_t)NE*4);

  // adaptive bf16 G-chunk (deterministic per ws_size); L3-resident cap
  size_t used = (size_t)(p - (char*)d_ws);
  size_t rem = (ws_size > used) ? (ws_size - used) : 0;
  long long Cll = (long long)(rem / ((size_t)NGX*2));
  int C = (Cll > 7552) ? 7552 : (int)Cll;
  C &= ~127;                  // multiple of 128 (ggemm m-tile)
  if (C < 128)  C = 128;
  ushort_t* G = (ushort_t*)alloc((size_t)C*NGX*2);
  int nch = (NN + C - 1) / C;

  k_sniff<<<1, 256, 0, stream>>>((const ushort_t*)d_in[p_nf], (const int*)d_in[p_dst], flags);
  k_canon_all<<<dim3((maxn+255)/256, 15), 256, 0, stream>>>(ca, flags);
  k_canoni<<<(NE+255)/256, 256, 0, stream>>>(d_in[p_src], srcc, NE, flags);
  k_canoni<<<(NE+255)/256, 256, 0, stream>>>(d_in[p_dst], dstc, NE, flags);

  k_proj <<<NN/4,  256, 0, stream>>>(nf, Wp, bp, hid, hidb);
  k_emlp <<<NE/2,  256, 0, stream>>>(ef, W1, b1, tfp);
  k_w2rtx<<<(NGX*DD+255)/256, 256, 0, stream>>>(W2, b2, w2rtx);
  k_zero <<<(4*NN+255)/256, 256, 0, stream>>>(degall, 4*NN);
  k_deg  <<<(NE+255)/256, 256, 0, stream>>>(dstc, deg);
  k_deg  <<<(NE+255)/256, 256, 0, stream>>>(srcc, deg2);
  k_scan <<<1, 256, 0, stream>>>(deg, rowp, invd);
  k_scan <<<1, 256, 0, stream>>>(deg2, rowp2, invd2);
  k_scatter<<<(NE+255)/256, 256, 0, stream>>>(dstc, rowp, cursor, eidx);
  k_scatter<<<(NE+255)/256, 256, 0, stream>>>(srcc, rowp2, cursor2, eidx2);

  for (int s = 0; s < NSTEPS; ++s){
    for (int c = 0; c < nch; ++c){
      int chunk0 = c*C;
      int cact = (NN - chunk0 < C) ? (NN - chunk0) : C;
      k_ggemm<<<dim3(NGX/64, (cact+127)/128), 256, 0, stream>>>(hidb, w2rtx, G, chunk0, cact);
      k_edge <<<cact, 256, 0, stream>>>(tfp, G, rowp2, eidx2, msg, chunk0);
    }
    k_aggrbn<<<NPART, 256, 0, stream>>>(msg, rowp, eidx, invd, cb, rst, part);
    k_bnf   <<<1, 128, 0, stream>>>(part, stats);
    k_gru   <<<NPARTG, 256, 0, stream>>>(rst, stats, gam, bet, Wih, Whh, bih, bhh,
                                         hid, hidb, out, (s == NSTEPS-1) ? 1 : 0);
  }
}

// Round 15
// 1432.600 us; speedup vs baseline: 1.1243x; 1.0394x over previous
//
#include <hip/hip_runtime.h>
#include <math.h>

#define NN 15000      // nodes
#define NE 60000      // edges
#define DIN 74
#define DEIN 12
#define DD 64         // node feat dim
#define EH 128        // edge hidden
#define NG 8192       // EH*DD
#define NGX 8256      // NG + 64 (Bh fold)
#define NSTEPS 6
#define NPART 938     // ceil(NN/16)  (aggrbn)
#define NPARTG 469    // ceil(NN/32)  (gru)

typedef unsigned short ushort_t;
typedef __attribute__((ext_vector_type(8))) short short8v;
typedef __attribute__((ext_vector_type(4))) float float4v;

__device__ __forceinline__ float bsf(unsigned short u){
  union { unsigned int i; float f; } v; v.i = ((unsigned int)u) << 16; return v.f;
}
__device__ __forceinline__ float blo(unsigned int u){
  union { unsigned int i; float f; } v; v.i = u << 16; return v.f;
}
__device__ __forceinline__ float bhi(unsigned int u){
  union { unsigned int i; float f; } v; v.i = u & 0xffff0000u; return v.f;
}
__device__ __forceinline__ unsigned short fsb(float f){
  union { float f; unsigned int i; } v; v.f = f;
  unsigned int x = v.i;
  return (unsigned short)((x + 0x7FFFu + ((x >> 16) & 1u)) >> 16);
}

// ---------- dtype sniff
__global__ void k_sniff(const ushort_t* __restrict__ nf16,
                        const int* __restrict__ dsti, int* __restrict__ flags){
  __shared__ int cnt[2];
  int t = threadIdx.x;
  if (t < 2) cnt[t] = 0;
  __syncthreads();
  int bad = 0;
  for (int i = t; i < 1024; i += 256){
    unsigned short u = nf16[2*i];
    int e = (u >> 7) & 0xFF;
    if (e < 96 || e > 159) bad++;
  }
  if (bad) atomicAdd(&cnt[0], bad);
  if (t < 256 && dsti[2*t+1] == 0) atomicAdd(&cnt[1], 1);
  __syncthreads();
  if (t == 0){
    flags[0] = (cnt[0] > 300) ? 1 : 0;
    flags[1] = (cnt[1] > 250) ? 1 : 0;
  }
}

// ---------- batched canonicalization: 15 tensors in one dispatch
struct CanonArgs {
  const void* in[15];
  float* out[15];
  int n[15];
};
__global__ void k_canon_all(CanonArgs a, const int* __restrict__ flags){
  int j = blockIdx.y;
  int n = a.n[j];
  int fp32 = flags[0];
  const void* in = a.in[j];
  float* out = a.out[j];
  for (int i = blockIdx.x*256 + threadIdx.x; i < n; i += gridDim.x*256){
    if (fp32) out[i] = ((const float*)in)[i];
    else      out[i] = bsf(((const ushort_t*)in)[i]);
  }
}
__global__ void k_canoni(const void* __restrict__ in, int* __restrict__ out,
                         int n, const int* __restrict__ flags){
  int i = blockIdx.x*256 + threadIdx.x;
  if (i >= n) return;
  long long v = flags[1] ? ((const long long*)in)[i]
                         : (long long)((const int*)in)[i];
  int vi = (int)v;
  if (vi < 0) vi = 0;
  if (vi >= NN) vi = NN-1;
  out[i] = vi;
}

// ---------- one-time: h0 = relu(nf @ W_proj + b_proj) -> fp32 + bf16 shadow
__global__ void k_proj(const float* __restrict__ nf, const float* __restrict__ Wp,
                       const float* __restrict__ bp, float* __restrict__ hid,
                       ushort_t* __restrict__ hidb){
  __shared__ float nfl[4][DIN];
  int t = threadIdx.x, blk = blockIdx.x;
  for (int idx = t; idx < 4*DIN; idx += 256){
    int vl = idx / DIN, i = idx - vl*DIN;
    nfl[vl][i] = nf[(size_t)(blk*4+vl)*DIN + i];
  }
  __syncthreads();
  int vl = t >> 6, o = t & 63;
  int v = blk*4 + vl;
  float acc = bp[o];
  for (int i = 0; i < DIN; ++i) acc += nfl[vl][i] * Wp[i*DD + o];
  float r = fmaxf(acc, 0.f);
  hid[(size_t)v*DD + o] = r;
  hidb[(size_t)v*DD + o] = fsb(r);
}

// ---------- one-time: t = relu(ef @ W_e1 + b_e1), fp32
__global__ void k_emlp(const float* __restrict__ ef, const float* __restrict__ W1,
                       const float* __restrict__ b1, float* __restrict__ tfp){
  __shared__ float efl[2][DEIN];
  int t = threadIdx.x, blk = blockIdx.x;
  if (t < 2*DEIN){
    int el = t / DEIN, i = t - el*DEIN;
    efl[el][i] = ef[(size_t)(blk*2+el)*DEIN + i];
  }
  __syncthreads();
  int el = t >> 7, c = t & 127;
  float acc = b1[c];
  for (int i = 0; i < DEIN; ++i) acc += efl[el][i] * W1[i*EH + c];
  tfp[(size_t)(blk*2+el)*EH + c] = fmaxf(acc, 0.f);
}

// ---------- one-time: w2rtx rows permuted so G comes out o-major
__global__ void k_w2rtx(const float* __restrict__ W2, const float* __restrict__ b2,
                        ushort_t* __restrict__ w2rtx){
  int idx = blockIdx.x*256 + threadIdx.x;
  if (idx < NGX*DD){
    int n = idx >> 6, i = idx & 63;
    float v;
    if (n < NG){
      int o = n >> 7, k = n & 127;
      v = W2[(size_t)k*4096 + i*64 + o];
    } else {
      v = b2[i*64 + (n - NG)];
    }
    w2rtx[idx] = fsb(v);
  }
}

// ---------- CSR build
__global__ void k_zero(int* __restrict__ p, int n){
  int i = blockIdx.x*256 + threadIdx.x;
  if (i < n) p[i] = 0;
}
__global__ void k_deg(const int* __restrict__ idxarr, int* __restrict__ deg){
  int e = blockIdx.x*256 + threadIdx.x;
  if (e < NE) atomicAdd(&deg[idxarr[e]], 1);
}
__global__ void k_scan(const int* __restrict__ deg, int* __restrict__ rowp,
                       float* __restrict__ invd){
  __shared__ int ssum[256];
  int t = threadIdx.x;
  const int STRIP = (NN + 255) / 256;
  int lo = t*STRIP, hi = (lo + STRIP < NN) ? lo + STRIP : NN;
  int s = 0;
  for (int i = lo; i < hi; ++i) s += deg[i];
  ssum[t] = s;
  __syncthreads();
  if (t == 0){
    int acc = 0;
    for (int i = 0; i < 256; ++i){ int v = ssum[i]; ssum[i] = acc; acc += v; }
  }
  __syncthreads();
  int acc = ssum[t];
  for (int i = lo; i < hi; ++i){
    rowp[i] = acc;
    int d = deg[i];
    invd[i] = (d > 0) ? 1.0f/(float)d : 0.0f;
    acc += d;
  }
  if (t == 255) rowp[NN] = acc;
}
__global__ void k_scatter(const int* __restrict__ idxarr, const int* __restrict__ rowp,
                          int* __restrict__ cursor, int* __restrict__ eidx){
  int e = blockIdx.x*256 + threadIdx.x;
  if (e < NE){
    int d = idxarr[e];
    int pos = atomicAdd(&cursor[d], 1);
    eidx[rowp[d] + pos] = e;
  }
}

// ---------- per chunk: G[m][n'] = hidb[chunk0+m] @ w2rtx  (bf16 MFMA, 128x64 tile)
__global__ __launch_bounds__(256) void k_ggemm(const ushort_t* __restrict__ hidb,
        const ushort_t* __restrict__ w2rtx, ushort_t* __restrict__ G,
        int chunk0, int cact){
  __shared__ __align__(16) ushort_t As[128][72];  // 18.4 KB
  __shared__ __align__(16) ushort_t Bs[64][72];   //  9.2 KB
  int t = threadIdx.x;
  int n0 = blockIdx.x * 64;
  int m0 = blockIdx.y * 128;
  #pragma unroll
  for (int it = 0; it < 6; ++it){
    int cid = t + it*256;
    int r = cid >> 3, ko = (cid & 7) * 8;
    if (r < 128){
      int gm = chunk0 + m0 + r; if (gm >= NN) gm = NN-1;  // clamp; store guarded
      *(uint4*)&As[r][ko] = *(const uint4*)(hidb + (size_t)gm*DD + ko);
    } else {
      *(uint4*)&Bs[r-128][ko] = *(const uint4*)(w2rtx + (size_t)(n0 + r-128)*DD + ko);
    }
  }
  __syncthreads();
  int w = t >> 6, lane = t & 63;
  int lrow = lane & 15, quad = lane >> 4;
  float4v acc[2][4];
  #pragma unroll
  for (int mt = 0; mt < 2; ++mt)
    #pragma unroll
    for (int nt = 0; nt < 4; ++nt) acc[mt][nt] = (float4v){0.f,0.f,0.f,0.f};
  #pragma unroll
  for (int ks = 0; ks < 2; ++ks){
    short8v a0 = *(const short8v*)&As[w*32 + lrow][ks*32 + quad*8];
    short8v a1 = *(const short8v*)&As[w*32 + 16 + lrow][ks*32 + quad*8];
    #pragma unroll
    for (int nt = 0; nt < 4; ++nt){
      short8v b = *(const short8v*)&Bs[nt*16 + lrow][ks*32 + quad*8];
      acc[0][nt] = __builtin_amdgcn_mfma_f32_16x16x32_bf16(a0, b, acc[0][nt], 0, 0, 0);
      acc[1][nt] = __builtin_amdgcn_mfma_f32_16x16x32_bf16(a1, b, acc[1][nt], 0, 0, 0);
    }
  }
  #pragma unroll
  for (int mt = 0; mt < 2; ++mt){
    #pragma unroll
    for (int nt = 0; nt < 4; ++nt){
      int col = n0 + nt*16 + lrow;
      #pragma unroll
      for (int reg = 0; reg < 4; ++reg){
        int m = m0 + w*32 + mt*16 + quad*4 + reg;
        if (m < cact) G[(size_t)m*NGX + col] = fsb(acc[mt][nt][reg]);
      }
    }
  }
}

// ---------- per chunk: msg[e,o] = sum_k t[e,k]*G[src][o*128+k] + G[src][8192+o]
__global__ __launch_bounds__(256) void k_edge(const float* __restrict__ tfp,
      const ushort_t* __restrict__ G,
      const int* __restrict__ rowp2, const int* __restrict__ eidx2,
      float* __restrict__ msg, int chunk0){
  __shared__ __align__(16) ushort_t gl[NG];    // 16 KB, swizzled per-o chunks
  __shared__ __align__(16) ushort_t bhl[64];
  __shared__ __align__(16) float tl[4][128];   // 2 KB
  __shared__ int eids[4];
  int t = threadIdx.x;
  int vloc = blockIdx.x;
  int v = chunk0 + vloc;
  int b = rowp2[v], e_end = rowp2[v+1];
  if (b == e_end) return;                      // block-uniform
  const ushort_t* grow = G + (size_t)vloc*NGX;
  for (int idx = t; idx < 1032; idx += 256){   // 1032 uint4 = 8256 bf16, coalesced
    uint4 val = *(const uint4*)(grow + idx*8);
    if (idx < 1024){
      int o = idx >> 4, c = idx & 15;
      *(uint4*)&gl[o*128 + ((c ^ (o & 15)) << 3)] = val;
    } else {
      *(uint4*)&bhl[(idx - 1024)*8] = val;
    }
  }
  int w = t >> 6, o = t & 63;
  int sw = o & 15;
  const uint4* gv = (const uint4*)&gl[o*128];  // 16 swizzled chunks of 8 bf16
  for (int base = b; base < e_end; base += 4){
    __syncthreads();                           // also covers gl/bhl visibility
    if (t < 4){
      int ei = base + t;
      eids[t] = (ei < e_end) ? eidx2[ei] : -1;
    }
    __syncthreads();
    for (int idx = t; idx < 512; idx += 256){
      int slot = idx >> 7, k = idx & 127;
      int e = eids[slot];
      tl[slot][k] = (e >= 0) ? tfp[(size_t)e*EH + k] : 0.f;
    }
    __syncthreads();
    int e = eids[w];
    if (e >= 0){
      float acc = bsf(bhl[o]);
      #pragma unroll
      for (int c = 0; c < 16; ++c){
        uint4 g8 = gv[c ^ sw];
        float4 ta = *(const float4*)&tl[w][c*8];
        float4 tb = *(const float4*)&tl[w][c*8 + 4];
        acc += ta.x*blo(g8.x) + ta.y*bhi(g8.x) + ta.z*blo(g8.y) + ta.w*bhi(g8.y);
        acc += tb.x*blo(g8.z) + tb.y*bhi(g8.z) + tb.z*blo(g8.w) + tb.w*bhi(g8.w);
      }
      msg[(size_t)e*DD + o] = acc;
    }
  }
}

// ---------- per step: rst = mean msg + bias; fused BN column partials
__global__ __launch_bounds__(256) void k_aggrbn(const float* __restrict__ msg,
      const int* __restrict__ rowp, const int* __restrict__ eidx,
      const float* __restrict__ invd, const float* __restrict__ cbias,
      float* __restrict__ rst, float* __restrict__ part){
  __shared__ float ls[4][64], ls2[4][64];
  int t = threadIdx.x, blk = blockIdx.x;
  int o = t & 63, w = t >> 6;
  float cb = cbias[o];
  float s = 0.f, s2 = 0.f;
  #pragma unroll
  for (int j = 0; j < 4; ++j){
    int v = blk*16 + w*4 + j;
    if (v < NN){
      float acc = 0.f;
      int b = rowp[v], e2 = rowp[v+1];
      for (int idx = b; idx < e2; ++idx)
        acc += msg[(size_t)eidx[idx]*DD + o];
      float r = acc*invd[v] + cb;
      rst[(size_t)v*DD + o] = r;
      s += r; s2 += r*r;
    }
  }
  ls[w][o] = s; ls2[w][o] = s2;
  __syncthreads();
  if (w == 0){
    part[blk*128 + o]      = ls[0][o]+ls[1][o]+ls[2][o]+ls[3][o];
    part[blk*128 + 64 + o] = ls2[0][o]+ls2[1][o]+ls2[2][o]+ls2[3][o];
  }
}
__global__ void k_bnf(const float* __restrict__ part, float* __restrict__ stats){
  __shared__ float sh[128];
  int t = threadIdx.x;  // 128 threads
  float s = 0.f;
  for (int b = 0; b < NPART; ++b) s += part[b*128 + t];
  sh[t] = s;
  __syncthreads();
  if (t < 64){
    float mu = sh[t] / (float)NN;
    float var = sh[64+t] / (float)NN - mu*mu;
    if (var < 0.f) var = 0.f;
    stats[t] = mu;
    stats[64 + t] = rsqrtf(var + 1e-5f);
  }
}

// ---------- per step: GRU, 32 nodes/block, TRANSPOSED activation staging:
// mlT/hlT[i][n] so the per-i inner loop reads activations as wave-uniform
// broadcast ds_read_b128 (4 per i) instead of 16 scalar broadcasts.
__global__ __launch_bounds__(256) void k_gru(const float* __restrict__ rst,
      const float* __restrict__ stats,
      const float* __restrict__ gamma, const float* __restrict__ beta,
      const float* __restrict__ Wih, const float* __restrict__ Whh,
      const float* __restrict__ bih, const float* __restrict__ bhh,
      float* __restrict__ hid, ushort_t* __restrict__ hidb,
      float* __restrict__ out, int write_out){
  __shared__ __align__(16) float mlT[64][36], hlT[64][36];  // 18.4 KB
  __shared__ float wtI[64][65], wtH[64][65];                // 33.3 KB
  int t = threadIdx.x, blk = blockIdx.x;
  int o = t & 63, w = t >> 6;
  float st_mu = stats[o], st_rs = stats[64+o], ga = gamma[o], be = beta[o];
  float hprev[8];
  #pragma unroll
  for (int j = 0; j < 8; ++j){
    int n = w*8 + j;
    int v = blk*32 + n;
    float x  = (v < NN) ? rst[(size_t)v*DD + o] : 0.f;
    float hp = (v < NN) ? hid[(size_t)v*DD + o] : 0.f;
    mlT[o][n] = fmaxf((x - st_mu)*st_rs*ga + be, 0.f);
    hlT[o][n] = hp;
    hprev[j] = hp;
  }
  float aR[8], aZ[8], aNi[8], aNh[8];
  {
    float bR = bih[o] + bhh[o];
    float bZ = bih[64+o] + bhh[64+o];
    float bNi = bih[128+o], bNh = bhh[128+o];
    #pragma unroll
    for (int j = 0; j < 8; ++j){ aR[j]=bR; aZ[j]=bZ; aNi[j]=bNi; aNh[j]=bNh; }
  }
  int nb = w*8;   // this wave's node-group base (wave-uniform)
  #pragma unroll
  for (int g = 0; g < 3; ++g){
    __syncthreads();
    for (int idx = t; idx < 4096; idx += 256){
      int row = idx >> 6, i = idx & 63;       // row = gate-output index
      wtI[i][row] = Wih[(size_t)(g*64+row)*64 + i];
      wtH[i][row] = Whh[(size_t)(g*64+row)*64 + i];
    }
    __syncthreads();
    for (int i = 0; i < 64; ++i){
      float wi = wtI[i][o], wh = wtH[i][o];
      float4 ma = *(const float4*)&mlT[i][nb];      // broadcast b128
      float4 mb = *(const float4*)&mlT[i][nb+4];
      float4 ha = *(const float4*)&hlT[i][nb];
      float4 hb = *(const float4*)&hlT[i][nb+4];
      float mv[8] = {ma.x,ma.y,ma.z,ma.w, mb.x,mb.y,mb.z,mb.w};
      float hv[8] = {ha.x,ha.y,ha.z,ha.w, hb.x,hb.y,hb.z,hb.w};
      #pragma unroll
      for (int j = 0; j < 8; ++j){
        if (g == 0)      aR[j]  += mv[j]*wi + hv[j]*wh;
        else if (g == 1) aZ[j]  += mv[j]*wi + hv[j]*wh;
        else           { aNi[j] += mv[j]*wi; aNh[j] += hv[j]*wh; }
      }
    }
  }
  #pragma unroll
  for (int j = 0; j < 8; ++j){
    int v = blk*32 + w*8 + j;
    if (v < NN){
      float r  = 1.f/(1.f+__expf(-aR[j]));
      float z  = 1.f/(1.f+__expf(-aZ[j]));
      float nn_= tanhf(aNi[j] + r*aNh[j]);
      float hnew = (1.f - z)*nn_ + z*hprev[j];
      hid[(size_t)v*DD + o] = hnew;
      hidb[(size_t)v*DD + o] = fsb(hnew);
      if (write_out) out[(size_t)v*DD + o] = hnew;
    }
  }
}

extern "C" void kernel_launch(void* const* d_in, const int* in_sizes, int n_in,
                              void* d_out, int out_size, void* d_ws, size_t ws_size,
                              hipStream_t stream){
  (void)out_size;
  float* out = (float*)d_out;

  // resolve input positions by size (== dict order on this instance)
  int p_nf=-1,p_ef=-1,p_src=-1,p_dst=-1,p_Wp=-1,p_bp=-1,p_W1=-1,p_b1=-1,
      p_W2=-1,p_b2=-1,p_cb=-1,p_gam=-1,p_bet=-1,p_Wih=-1,p_Whh=-1,p_bih=-1,p_bhh=-1;
  int c60000=0,c64=0,c12288=0,c192=0;
  for (int i = 0; i < n_in; ++i){
    switch (in_sizes[i]){
      case 1110000: p_nf = i; break;
      case 720000:  p_ef = i; break;
      case 60000:   if (c60000++ == 0) p_src = i; else p_dst = i; break;
      case 4736:    p_Wp = i; break;
      case 64:      { if (c64==0) p_bp=i; else if (c64==1) p_cb=i;
                      else if (c64==2) p_gam=i; else p_bet=i; c64++; } break;
      case 1536:    p_W1 = i; break;
      case 128:     p_b1 = i; break;
      case 524288:  p_W2 = i; break;
      case 4096:    p_b2 = i; break;
      case 12288:   if (c12288++ == 0) p_Wih = i; else p_Whh = i; break;
      case 192:     if (c192++ == 0) p_bih = i; else p_bhh = i; break;
      default: break;
    }
  }

  char* p = (char*)d_ws;
  auto alloc = [&](size_t bytes)->char*{
    char* r = p; p += (bytes + 255) & ~(size_t)255; return r;
  };
  int* flags = (int*)alloc(256);
  const int FPOS[15] = {p_nf,p_ef,p_Wp,p_bp,p_W1,p_b1,p_W2,p_b2,p_cb,p_gam,p_bet,
                        p_Wih,p_Whh,p_bih,p_bhh};
  CanonArgs ca;
  int maxn = 0;
  for (int j = 0; j < 15; ++j){
    int n = in_sizes[FPOS[j]];
    ca.in[j]  = d_in[FPOS[j]];
    ca.out[j] = (float*)alloc((size_t)n * 4);
    ca.n[j]   = n;
    if (n > maxn) maxn = n;
  }
  const float* nf  = ca.out[0];  const float* ef  = ca.out[1];
  const float* Wp  = ca.out[2];  const float* bp  = ca.out[3];
  const float* W1  = ca.out[4];  const float* b1  = ca.out[5];
  const float* W2  = ca.out[6];  const float* b2  = ca.out[7];
  const float* cb  = ca.out[8];  const float* gam = ca.out[9];
  const float* bet = ca.out[10]; const float* Wih = ca.out[11];
  const float* Whh = ca.out[12]; const float* bih = ca.out[13];
  const float* bhh = ca.out[14];
  int* srcc = (int*)alloc((size_t)NE*4);
  int* dstc = (int*)alloc((size_t)NE*4);

  float* tfp      = (float*)alloc((size_t)NE*EH*4);     // 30.7 MB
  ushort_t* w2rtx = (ushort_t*)alloc((size_t)NGX*DD*2); // 1.06 MB
  float* hid      = (float*)alloc((size_t)NN*DD*4);
  ushort_t* hidb  = (ushort_t*)alloc((size_t)NN*DD*2);
  float* msg      = (float*)alloc((size_t)NE*DD*4);     // 15.4 MB
  float* rst      = (float*)alloc((size_t)NN*DD*4);
  float* part     = (float*)alloc((size_t)NPART*128*4);
  float* stats    = (float*)alloc(128*4);
  int* degall     = (int*)alloc((size_t)4*NN*4);
  int* deg  = degall;        int* cursor  = degall + NN;
  int* deg2 = degall + 2*NN; int* cursor2 = degall + 3*NN;
  int* rowp   = (int*)alloc((size_t)(NN+1)*4);
  float* invd = (float*)alloc((size_t)NN*4);
  int* eidx   = (int*)alloc((size_t)NE*4);
  int* rowp2  = (int*)alloc((size_t)(NN+1)*4);
  float* invd2= (float*)alloc((size_t)NN*4);
  int* eidx2  = (int*)alloc((size_t)NE*4);

  // adaptive bf16 G-chunk (deterministic per ws_size); L3-resident cap
  size_t used = (size_t)(p - (char*)d_ws);
  size_t rem = (ws_size > used) ? (ws_size - used) : 0;
  long long Cll = (long long)(rem / ((size_t)NGX*2));
  int C = (Cll > 7552) ? 7552 : (int)Cll;
  C &= ~127;                  // multiple of 128 (ggemm m-tile)
  if (C < 128)  C = 128;
  ushort_t* G = (ushort_t*)alloc((size_t)C*NGX*2);
  int nch = (NN + C - 1) / C;

  k_sniff<<<1, 256, 0, stream>>>((const ushort_t*)d_in[p_nf], (const int*)d_in[p_dst], flags);
  k_canon_all<<<dim3((maxn+255)/256, 15), 256, 0, stream>>>(ca, flags);
  k_canoni<<<(NE+255)/256, 256, 0, stream>>>(d_in[p_src], srcc, NE, flags);
  k_canoni<<<(NE+255)/256, 256, 0, stream>>>(d_in[p_dst], dstc, NE, flags);

  k_proj <<<NN/4,  256, 0, stream>>>(nf, Wp, bp, hid, hidb);
  k_emlp <<<NE/2,  256, 0, stream>>>(ef, W1, b1, tfp);
  k_w2rtx<<<(NGX*DD+255)/256, 256, 0, stream>>>(W2, b2, w2rtx);
  k_zero <<<(4*NN+255)/256, 256, 0, stream>>>(degall, 4*NN);
  k_deg  <<<(NE+255)/256, 256, 0, stream>>>(dstc, deg);
  k_deg  <<<(NE+255)/256, 256, 0, stream>>>(srcc, deg2);
  k_scan <<<1, 256, 0, stream>>>(deg, rowp, invd);
  k_scan <<<1, 256, 0, stream>>>(deg2, rowp2, invd2);
  k_scatter<<<(NE+255)/256, 256, 0, stream>>>(dstc, rowp, cursor, eidx);
  k_scatter<<<(NE+255)/256, 256, 0, stream>>>(srcc, rowp2, cursor2, eidx2);

  for (int s = 0; s < NSTEPS; ++s){
    for (int c = 0; c < nch; ++c){
      int chunk0 = c*C;
      int cact = (NN - chunk0 < C) ? (NN - chunk0) : C;
      k_ggemm<<<dim3(NGX/64, (cact+127)/128), 256, 0, stream>>>(hidb, w2rtx, G, chunk0, cact);
      k_edge <<<cact, 256, 0, stream>>>(tfp, G, rowp2, eidx2, msg, chunk0);
    }
    k_aggrbn<<<NPART, 256, 0, stream>>>(msg, rowp, eidx, invd, cb, rst, part);
    k_bnf   <<<1, 128, 0, stream>>>(part, stats);
    k_gru   <<<NPARTG, 256, 0, stream>>>(rst, stats, gam, bet, Wih, Whh, bih, bhh,
                                         hid, hidb, out, (s == NSTEPS-1) ? 1 : 0);
  }
}

// Round 16
// 1328.260 us; speedup vs baseline: 1.2127x; 1.0786x over previous
//
#include <hip/hip_runtime.h>
#include <math.h>

#define NN 15000      // nodes
#define NE 60000      // edges
#define DIN 74
#define DEIN 12
#define DD 64         // node feat dim
#define EH 128        // edge hidden
#define NG 8192       // EH*DD
#define NGX 8256      // NG + 64 (Bh fold)
#define NSTEPS 6
#define NBN 59        // ceil(NN/256)  (BN partials)
#define NPARTG 469    // ceil(NN/32)   (gru)

typedef unsigned short ushort_t;
typedef __attribute__((ext_vector_type(8))) short short8v;
typedef __attribute__((ext_vector_type(4))) float float4v;

__device__ __forceinline__ float bsf(unsigned short u){
  union { unsigned int i; float f; } v; v.i = ((unsigned int)u) << 16; return v.f;
}
__device__ __forceinline__ float blo(unsigned int u){
  union { unsigned int i; float f; } v; v.i = u << 16; return v.f;
}
__device__ __forceinline__ float bhi(unsigned int u){
  union { unsigned int i; float f; } v; v.i = u & 0xffff0000u; return v.f;
}
__device__ __forceinline__ unsigned short fsb(float f){
  union { float f; unsigned int i; } v; v.f = f;
  unsigned int x = v.i;
  return (unsigned short)((x + 0x7FFFu + ((x >> 16) & 1u)) >> 16);
}

// ---------- dtype sniff
__global__ void k_sniff(const ushort_t* __restrict__ nf16,
                        const int* __restrict__ dsti, int* __restrict__ flags){
  __shared__ int cnt[2];
  int t = threadIdx.x;
  if (t < 2) cnt[t] = 0;
  __syncthreads();
  int bad = 0;
  for (int i = t; i < 1024; i += 256){
    unsigned short u = nf16[2*i];
    int e = (u >> 7) & 0xFF;
    if (e < 96 || e > 159) bad++;
  }
  if (bad) atomicAdd(&cnt[0], bad);
  if (t < 256 && dsti[2*t+1] == 0) atomicAdd(&cnt[1], 1);
  __syncthreads();
  if (t == 0){
    flags[0] = (cnt[0] > 300) ? 1 : 0;
    flags[1] = (cnt[1] > 250) ? 1 : 0;
  }
}

// ---------- batched canonicalization: 15 tensors in one dispatch
struct CanonArgs {
  const void* in[15];
  float* out[15];
  int n[15];
};
__global__ void k_canon_all(CanonArgs a, const int* __restrict__ flags){
  int j = blockIdx.y;
  int n = a.n[j];
  int fp32 = flags[0];
  const void* in = a.in[j];
  float* out = a.out[j];
  for (int i = blockIdx.x*256 + threadIdx.x; i < n; i += gridDim.x*256){
    if (fp32) out[i] = ((const float*)in)[i];
    else      out[i] = bsf(((const ushort_t*)in)[i]);
  }
}
__global__ void k_canoni(const void* __restrict__ in, int* __restrict__ out,
                         int n, const int* __restrict__ flags){
  int i = blockIdx.x*256 + threadIdx.x;
  if (i >= n) return;
  long long v = flags[1] ? ((const long long*)in)[i]
                         : (long long)((const int*)in)[i];
  int vi = (int)v;
  if (vi < 0) vi = 0;
  if (vi >= NN) vi = NN-1;
  out[i] = vi;
}

// ---------- one-time: h0 = relu(nf @ W_proj + b_proj) -> fp32 + bf16 shadow
__global__ void k_proj(const float* __restrict__ nf, const float* __restrict__ Wp,
                       const float* __restrict__ bp, float* __restrict__ hid,
                       ushort_t* __restrict__ hidb){
  __shared__ float nfl[4][DIN];
  int t = threadIdx.x, blk = blockIdx.x;
  for (int idx = t; idx < 4*DIN; idx += 256){
    int vl = idx / DIN, i = idx - vl*DIN;
    nfl[vl][i] = nf[(size_t)(blk*4+vl)*DIN + i];
  }
  __syncthreads();
  int vl = t >> 6, o = t & 63;
  int v = blk*4 + vl;
  float acc = bp[o];
  for (int i = 0; i < DIN; ++i) acc += nfl[vl][i] * Wp[i*DD + o];
  float r = fmaxf(acc, 0.f);
  hid[(size_t)v*DD + o] = r;
  hidb[(size_t)v*DD + o] = fsb(r);
}

// ---------- one-time: t = relu(ef @ W_e1 + b_e1), fp32
__global__ void k_emlp(const float* __restrict__ ef, const float* __restrict__ W1,
                       const float* __restrict__ b1, float* __restrict__ tfp){
  __shared__ float efl[2][DEIN];
  int t = threadIdx.x, blk = blockIdx.x;
  if (t < 2*DEIN){
    int el = t / DEIN, i = t - el*DEIN;
    efl[el][i] = ef[(size_t)(blk*2+el)*DEIN + i];
  }
  __syncthreads();
  int el = t >> 7, c = t & 127;
  float acc = b1[c];
  for (int i = 0; i < DEIN; ++i) acc += efl[el][i] * W1[i*EH + c];
  tfp[(size_t)(blk*2+el)*EH + c] = fmaxf(acc, 0.f);
}

// ---------- one-time: w2rtx rows permuted so G comes out o-major
__global__ void k_w2rtx(const float* __restrict__ W2, const float* __restrict__ b2,
                        ushort_t* __restrict__ w2rtx){
  int idx = blockIdx.x*256 + threadIdx.x;
  if (idx < NGX*DD){
    int n = idx >> 6, i = idx & 63;
    float v;
    if (n < NG){
      int o = n >> 7, k = n & 127;
      v = W2[(size_t)k*4096 + i*64 + o];
    } else {
      v = b2[i*64 + (n - NG)];
    }
    w2rtx[idx] = fsb(v);
  }
}

// ---------- CSR build (src only) + degree/invd for dst
__global__ void k_zero(int* __restrict__ p, int n){
  int i = blockIdx.x*256 + threadIdx.x;
  if (i < n) p[i] = 0;
}
__global__ void k_deg(const int* __restrict__ idxarr, int* __restrict__ deg){
  int e = blockIdx.x*256 + threadIdx.x;
  if (e < NE) atomicAdd(&deg[idxarr[e]], 1);
}
__global__ void k_invd(const int* __restrict__ deg, float* __restrict__ invd){
  int i = blockIdx.x*256 + threadIdx.x;
  if (i < NN){
    int d = deg[i];
    invd[i] = (d > 0) ? 1.0f/(float)d : 0.0f;
  }
}
__global__ void k_scan(const int* __restrict__ deg, int* __restrict__ rowp,
                       float* __restrict__ invd){
  __shared__ int ssum[256];
  int t = threadIdx.x;
  const int STRIP = (NN + 255) / 256;
  int lo = t*STRIP, hi = (lo + STRIP < NN) ? lo + STRIP : NN;
  int s = 0;
  for (int i = lo; i < hi; ++i) s += deg[i];
  ssum[t] = s;
  __syncthreads();
  if (t == 0){
    int acc = 0;
    for (int i = 0; i < 256; ++i){ int v = ssum[i]; ssum[i] = acc; acc += v; }
  }
  __syncthreads();
  int acc = ssum[t];
  for (int i = lo; i < hi; ++i){
    rowp[i] = acc;
    int d = deg[i];
    invd[i] = (d > 0) ? 1.0f/(float)d : 0.0f;
    acc += d;
  }
  if (t == 255) rowp[NN] = acc;
}
__global__ void k_scatter(const int* __restrict__ idxarr, const int* __restrict__ rowp,
                          int* __restrict__ cursor, int* __restrict__ eidx){
  int e = blockIdx.x*256 + threadIdx.x;
  if (e < NE){
    int d = idxarr[e];
    int pos = atomicAdd(&cursor[d], 1);
    eidx[rowp[d] + pos] = e;
  }
}

// ---------- per step: rst init to conv_bias (atomic accumulation target)
__global__ void k_rstinit(const float* __restrict__ cbias, float* __restrict__ rst){
  int i = blockIdx.x*256 + threadIdx.x;
  if (i < NN*DD) rst[i] = cbias[i & 63];
}

// ---------- per chunk: G[m][n'] = hidb[chunk0+m] @ w2rtx  (bf16 MFMA, 128x64 tile)
__global__ __launch_bounds__(256) void k_ggemm(const ushort_t* __restrict__ hidb,
        const ushort_t* __restrict__ w2rtx, ushort_t* __restrict__ G,
        int chunk0, int cact){
  __shared__ __align__(16) ushort_t As[128][72];  // 18.4 KB
  __shared__ __align__(16) ushort_t Bs[64][72];   //  9.2 KB
  int t = threadIdx.x;
  int n0 = blockIdx.x * 64;
  int m0 = blockIdx.y * 128;
  #pragma unroll
  for (int it = 0; it < 6; ++it){
    int cid = t + it*256;
    int r = cid >> 3, ko = (cid & 7) * 8;
    if (r < 128){
      int gm = chunk0 + m0 + r; if (gm >= NN) gm = NN-1;  // clamp; store guarded
      *(uint4*)&As[r][ko] = *(const uint4*)(hidb + (size_t)gm*DD + ko);
    } else {
      *(uint4*)&Bs[r-128][ko] = *(const uint4*)(w2rtx + (size_t)(n0 + r-128)*DD + ko);
    }
  }
  __syncthreads();
  int w = t >> 6, lane = t & 63;
  int lrow = lane & 15, quad = lane >> 4;
  float4v acc[2][4];
  #pragma unroll
  for (int mt = 0; mt < 2; ++mt)
    #pragma unroll
    for (int nt = 0; nt < 4; ++nt) acc[mt][nt] = (float4v){0.f,0.f,0.f,0.f};
  #pragma unroll
  for (int ks = 0; ks < 2; ++ks){
    short8v a0 = *(const short8v*)&As[w*32 + lrow][ks*32 + quad*8];
    short8v a1 = *(const short8v*)&As[w*32 + 16 + lrow][ks*32 + quad*8];
    #pragma unroll
    for (int nt = 0; nt < 4; ++nt){
      short8v b = *(const short8v*)&Bs[nt*16 + lrow][ks*32 + quad*8];
      acc[0][nt] = __builtin_amdgcn_mfma_f32_16x16x32_bf16(a0, b, acc[0][nt], 0, 0, 0);
      acc[1][nt] = __builtin_amdgcn_mfma_f32_16x16x32_bf16(a1, b, acc[1][nt], 0, 0, 0);
    }
  }
  #pragma unroll
  for (int mt = 0; mt < 2; ++mt){
    #pragma unroll
    for (int nt = 0; nt < 4; ++nt){
      int col = n0 + nt*16 + lrow;
      #pragma unroll
      for (int reg = 0; reg < 4; ++reg){
        int m = m0 + w*32 + mt*16 + quad*4 + reg;
        if (m < cact) G[(size_t)m*NGX + col] = fsb(acc[mt][nt][reg]);
      }
    }
  }
}

// ---------- per chunk: for each edge of node v: atomicAdd rst[dst] += inv*msg
__global__ __launch_bounds__(256) void k_edge(const float* __restrict__ tfp,
      const ushort_t* __restrict__ G,
      const int* __restrict__ rowp2, const int* __restrict__ eidx2,
      const int* __restrict__ dstc, const float* __restrict__ invd,
      float* __restrict__ rst, int chunk0){
  __shared__ __align__(16) ushort_t gl[NG];    // 16 KB, swizzled per-o chunks
  __shared__ __align__(16) ushort_t bhl[64];
  __shared__ __align__(16) float tl[4][128];   // 2 KB
  __shared__ int eids[4];
  int t = threadIdx.x;
  int vloc = blockIdx.x;
  int v = chunk0 + vloc;
  int b = rowp2[v], e_end = rowp2[v+1];
  if (b == e_end) return;                      // block-uniform
  const ushort_t* grow = G + (size_t)vloc*NGX;
  for (int idx = t; idx < 1032; idx += 256){   // 1032 uint4 = 8256 bf16, coalesced
    uint4 val = *(const uint4*)(grow + idx*8);
    if (idx < 1024){
      int o = idx >> 4, c = idx & 15;
      *(uint4*)&gl[o*128 + ((c ^ (o & 15)) << 3)] = val;
    } else {
      *(uint4*)&bhl[(idx - 1024)*8] = val;
    }
  }
  int w = t >> 6, o = t & 63;
  int sw = o & 15;
  const uint4* gv = (const uint4*)&gl[o*128];  // 16 swizzled chunks of 8 bf16
  for (int base = b; base < e_end; base += 4){
    __syncthreads();                           // also covers gl/bhl visibility
    if (t < 4){
      int ei = base + t;
      eids[t] = (ei < e_end) ? eidx2[ei] : -1;
    }
    __syncthreads();
    for (int idx = t; idx < 512; idx += 256){
      int slot = idx >> 7, k = idx & 127;
      int e = eids[slot];
      tl[slot][k] = (e >= 0) ? tfp[(size_t)e*EH + k] : 0.f;
    }
    __syncthreads();
    int e = eids[w];
    if (e >= 0){
      float acc = bsf(bhl[o]);
      #pragma unroll
      for (int c = 0; c < 16; ++c){
        uint4 g8 = gv[c ^ sw];
        float4 ta = *(const float4*)&tl[w][c*8];
        float4 tb = *(const float4*)&tl[w][c*8 + 4];
        acc += ta.x*blo(g8.x) + ta.y*bhi(g8.x) + ta.z*blo(g8.y) + ta.w*bhi(g8.y);
        acc += tb.x*blo(g8.z) + tb.y*bhi(g8.z) + tb.z*blo(g8.w) + tb.w*bhi(g8.w);
      }
      int d = dstc[e];
      atomicAdd(&rst[(size_t)d*DD + o], acc * invd[d]);
    }
  }
}

// ---------- per step: BN column partials over rst (dense)
__global__ void k_bnp(const float* __restrict__ rst, float* __restrict__ part){
  __shared__ float ls[256], ls2[256];
  int t = threadIdx.x, blk = blockIdx.x;
  int o = t & 63, gg = t >> 6;
  int r0 = blk*256;
  float s = 0.f, s2 = 0.f;
  for (int j = 0; j < 64; ++j){
    int r = r0 + gg + j*4;
    if (r < NN){
      float x = rst[(size_t)r*DD + o];
      s += x; s2 += x*x;
    }
  }
  ls[t] = s; ls2[t] = s2;
  __syncthreads();
  if (gg == 0){
    part[blk*128 + o]      = ls[o] + ls[64+o] + ls[128+o] + ls[192+o];
    part[blk*128 + 64 + o] = ls2[o] + ls2[64+o] + ls2[128+o] + ls2[192+o];
  }
}
__global__ void k_bnf(const float* __restrict__ part, float* __restrict__ stats){
  __shared__ float sh[128];
  int t = threadIdx.x;  // 128 threads
  float s = 0.f;
  for (int b = 0; b < NBN; ++b) s += part[b*128 + t];
  sh[t] = s;
  __syncthreads();
  if (t < 64){
    float mu = sh[t] / (float)NN;
    float var = sh[64+t] / (float)NN - mu*mu;
    if (var < 0.f) var = 0.f;
    stats[t] = mu;
    stats[64 + t] = rsqrtf(var + 1e-5f);
  }
}

// ---------- per step: GRU, 32 nodes/block, transposed activation staging
__global__ __launch_bounds__(256) void k_gru(const float* __restrict__ rst,
      const float* __restrict__ stats,
      const float* __restrict__ gamma, const float* __restrict__ beta,
      const float* __restrict__ Wih, const float* __restrict__ Whh,
      const float* __restrict__ bih, const float* __restrict__ bhh,
      float* __restrict__ hid, ushort_t* __restrict__ hidb,
      float* __restrict__ out, int write_out){
  __shared__ __align__(16) float mlT[64][36], hlT[64][36];  // 18.4 KB
  __shared__ float wtI[64][65], wtH[64][65];                // 33.3 KB
  int t = threadIdx.x, blk = blockIdx.x;
  int o = t & 63, w = t >> 6;
  float st_mu = stats[o], st_rs = stats[64+o], ga = gamma[o], be = beta[o];
  float hprev[8];
  #pragma unroll
  for (int j = 0; j < 8; ++j){
    int n = w*8 + j;
    int v = blk*32 + n;
    float x  = (v < NN) ? rst[(size_t)v*DD + o] : 0.f;
    float hp = (v < NN) ? hid[(size_t)v*DD + o] : 0.f;
    mlT[o][n] = fmaxf((x - st_mu)*st_rs*ga + be, 0.f);
    hlT[o][n] = hp;
    hprev[j] = hp;
  }
  float aR[8], aZ[8], aNi[8], aNh[8];
  {
    float bR = bih[o] + bhh[o];
    float bZ = bih[64+o] + bhh[64+o];
    float bNi = bih[128+o], bNh = bhh[128+o];
    #pragma unroll
    for (int j = 0; j < 8; ++j){ aR[j]=bR; aZ[j]=bZ; aNi[j]=bNi; aNh[j]=bNh; }
  }
  int nb = w*8;   // wave-uniform node-group base
  #pragma unroll
  for (int g = 0; g < 3; ++g){
    __syncthreads();
    for (int idx = t; idx < 4096; idx += 256){
      int row = idx >> 6, i = idx & 63;       // row = gate-output index
      wtI[i][row] = Wih[(size_t)(g*64+row)*64 + i];
      wtH[i][row] = Whh[(size_t)(g*64+row)*64 + i];
    }
    __syncthreads();
    for (int i = 0; i < 64; ++i){
      float wi = wtI[i][o], wh = wtH[i][o];
      float4 ma = *(const float4*)&mlT[i][nb];      // broadcast b128
      float4 mb = *(const float4*)&mlT[i][nb+4];
      float4 ha = *(const float4*)&hlT[i][nb];
      float4 hb = *(const float4*)&hlT[i][nb+4];
      float mv[8] = {ma.x,ma.y,ma.z,ma.w, mb.x,mb.y,mb.z,mb.w};
      float hv[8] = {ha.x,ha.y,ha.z,ha.w, hb.x,hb.y,hb.z,hb.w};
      #pragma unroll
      for (int j = 0; j < 8; ++j){
        if (g == 0)      aR[j]  += mv[j]*wi + hv[j]*wh;
        else if (g == 1) aZ[j]  += mv[j]*wi + hv[j]*wh;
        else           { aNi[j] += mv[j]*wi; aNh[j] += hv[j]*wh; }
      }
    }
  }
  #pragma unroll
  for (int j = 0; j < 8; ++j){
    int v = blk*32 + w*8 + j;
    if (v < NN){
      float r  = 1.f/(1.f+__expf(-aR[j]));
      float z  = 1.f/(1.f+__expf(-aZ[j]));
      float nn_= tanhf(aNi[j] + r*aNh[j]);
      float hnew = (1.f - z)*nn_ + z*hprev[j];
      hid[(size_t)v*DD + o] = hnew;
      hidb[(size_t)v*DD + o] = fsb(hnew);
      if (write_out) out[(size_t)v*DD + o] = hnew;
    }
  }
}

extern "C" void kernel_launch(void* const* d_in, const int* in_sizes, int n_in,
                              void* d_out, int out_size, void* d_ws, size_t ws_size,
                              hipStream_t stream){
  (void)out_size;
  float* out = (float*)d_out;

  // resolve input positions by size (== dict order on this instance)
  int p_nf=-1,p_ef=-1,p_src=-1,p_dst=-1,p_Wp=-1,p_bp=-1,p_W1=-1,p_b1=-1,
      p_W2=-1,p_b2=-1,p_cb=-1,p_gam=-1,p_bet=-1,p_Wih=-1,p_Whh=-1,p_bih=-1,p_bhh=-1;
  int c60000=0,c64=0,c12288=0,c192=0;
  for (int i = 0; i < n_in; ++i){
    switch (in_sizes[i]){
      case 1110000: p_nf = i; break;
      case 720000:  p_ef = i; break;
      case 60000:   if (c60000++ == 0) p_src = i; else p_dst = i; break;
      case 4736:    p_Wp = i; break;
      case 64:      { if (c64==0) p_bp=i; else if (c64==1) p_cb=i;
                      else if (c64==2) p_gam=i; else p_bet=i; c64++; } break;
      case 1536:    p_W1 = i; break;
      case 128:     p_b1 = i; break;
      case 524288:  p_W2 = i; break;
      case 4096:    p_b2 = i; break;
      case 12288:   if (c12288++ == 0) p_Wih = i; else p_Whh = i; break;
      case 192:     if (c192++ == 0) p_bih = i; else p_bhh = i; break;
      default: break;
    }
  }

  char* p = (char*)d_ws;
  auto alloc = [&](size_t bytes)->char*{
    char* r = p; p += (bytes + 255) & ~(size_t)255; return r;
  };
  int* flags = (int*)alloc(256);
  const int FPOS[15] = {p_nf,p_ef,p_Wp,p_bp,p_W1,p_b1,p_W2,p_b2,p_cb,p_gam,p_bet,
                        p_Wih,p_Whh,p_bih,p_bhh};
  CanonArgs ca;
  int maxn = 0;
  for (int j = 0; j < 15; ++j){
    int n = in_sizes[FPOS[j]];
    ca.in[j]  = d_in[FPOS[j]];
    ca.out[j] = (float*)alloc((size_t)n * 4);
    ca.n[j]   = n;
    if (n > maxn) maxn = n;
  }
  const float* nf  = ca.out[0];  const float* ef  = ca.out[1];
  const float* Wp  = ca.out[2];  const float* bp  = ca.out[3];
  const float* W1  = ca.out[4];  const float* b1  = ca.out[5];
  const float* W2  = ca.out[6];  const float* b2  = ca.out[7];
  const float* cb  = ca.out[8];  const float* gam = ca.out[9];
  const float* bet = ca.out[10]; const float* Wih = ca.out[11];
  const float* Whh = ca.out[12]; const float* bih = ca.out[13];
  const float* bhh = ca.out[14];
  int* srcc = (int*)alloc((size_t)NE*4);
  int* dstc = (int*)alloc((size_t)NE*4);

  float* tfp      = (float*)alloc((size_t)NE*EH*4);     // 30.7 MB
  ushort_t* w2rtx = (ushort_t*)alloc((size_t)NGX*DD*2); // 1.06 MB
  float* hid      = (float*)alloc((size_t)NN*DD*4);
  ushort_t* hidb  = (ushort_t*)alloc((size_t)NN*DD*2);
  float* rst      = (float*)alloc((size_t)NN*DD*4);
  float* part     = (float*)alloc((size_t)NBN*128*4);
  float* stats    = (float*)alloc(128*4);
  int* degall     = (int*)alloc((size_t)4*NN*4);
  int* deg  = degall;        // dst degrees (for invd)
  int* deg2 = degall + 2*NN; int* cursor2 = degall + 3*NN;
  float* invd = (float*)alloc((size_t)NN*4);
  int* rowp2  = (int*)alloc((size_t)(NN+1)*4);
  float* invd2= (float*)alloc((size_t)NN*4);
  int* eidx2  = (int*)alloc((size_t)NE*4);

  // adaptive bf16 G-chunk (deterministic per ws_size); L3-resident cap
  size_t used = (size_t)(p - (char*)d_ws);
  size_t rem = (ws_size > used) ? (ws_size - used) : 0;
  long long Cll = (long long)(rem / ((size_t)NGX*2));
  int C = (Cll > 7552) ? 7552 : (int)Cll;
  C &= ~127;                  // multiple of 128 (ggemm m-tile)
  if (C < 128)  C = 128;
  ushort_t* G = (ushort_t*)alloc((size_t)C*NGX*2);
  int nch = (NN + C - 1) / C;

  k_sniff<<<1, 256, 0, stream>>>((const ushort_t*)d_in[p_nf], (const int*)d_in[p_dst], flags);
  k_canon_all<<<dim3((maxn+255)/256, 15), 256, 0, stream>>>(ca, flags);
  k_canoni<<<(NE+255)/256, 256, 0, stream>>>(d_in[p_src], srcc, NE, flags);
  k_canoni<<<(NE+255)/256, 256, 0, stream>>>(d_in[p_dst], dstc, NE, flags);

  k_proj <<<NN/4,  256, 0, stream>>>(nf, Wp, bp, hid, hidb);
  k_emlp <<<NE/2,  256, 0, stream>>>(ef, W1, b1, tfp);
  k_w2rtx<<<(NGX*DD+255)/256, 256, 0, stream>>>(W2, b2, w2rtx);
  k_zero <<<(4*NN+255)/256, 256, 0, stream>>>(degall, 4*NN);
  k_deg  <<<(NE+255)/256, 256, 0, stream>>>(dstc, deg);
  k_deg  <<<(NE+255)/256, 256, 0, stream>>>(srcc, deg2);
  k_invd <<<(NN+255)/256, 256, 0, stream>>>(deg, invd);
  k_scan <<<1, 256, 0, stream>>>(deg2, rowp2, invd2);
  k_scatter<<<(NE+255)/256, 256, 0, stream>>>(srcc, rowp2, cursor2, eidx2);

  for (int s = 0; s < NSTEPS; ++s){
    k_rstinit<<<(NN*DD+255)/256, 256, 0, stream>>>(cb, rst);
    for (int c = 0; c < nch; ++c){
      int chunk0 = c*C;
      int cact = (NN - chunk0 < C) ? (NN - chunk0) : C;
      k_ggemm<<<dim3(NGX/64, (cact+127)/128), 256, 0, stream>>>(hidb, w2rtx, G, chunk0, cact);
      k_edge <<<cact, 256, 0, stream>>>(tfp, G, rowp2, eidx2, dstc, invd, rst, chunk0);
    }
    k_bnp <<<NBN, 256, 0, stream>>>(rst, part);
    k_bnf <<<1, 128, 0, stream>>>(part, stats);
    k_gru <<<NPARTG, 256, 0, stream>>>(rst, stats, gam, bet, Wih, Whh, bih, bhh,
                                       hid, hidb, out, (s == NSTEPS-1) ? 1 : 0);
  }
}

// Round 17
// 1267.597 us; speedup vs baseline: 1.2707x; 1.0479x over previous
//
#include <hip/hip_runtime.h>
#include <math.h>

#define NN 15000      // nodes
#define NE 60000      // edges
#define DIN 74
#define DEIN 12
#define DD 64         // node feat dim
#define EH 128        // edge hidden
#define NG 8192       // EH*DD
#define NGX 8256      // NG + 64 (Bh fold)
#define NSTEPS 6
#define NBN 59        // ceil(NN/256)  (BN partials)
#define KAB 384       // GRU split-A width: [m_hi,h_hi,m_lo,h_lo,m_hi,h_hi]

typedef unsigned short ushort_t;
typedef __attribute__((ext_vector_type(8))) short short8v;
typedef __attribute__((ext_vector_type(4))) float float4v;

__device__ __forceinline__ float bsf(unsigned short u){
  union { unsigned int i; float f; } v; v.i = ((unsigned int)u) << 16; return v.f;
}
__device__ __forceinline__ float blo(unsigned int u){
  union { unsigned int i; float f; } v; v.i = u << 16; return v.f;
}
__device__ __forceinline__ float bhi(unsigned int u){
  union { unsigned int i; float f; } v; v.i = u & 0xffff0000u; return v.f;
}
__device__ __forceinline__ unsigned short fsb(float f){
  union { float f; unsigned int i; } v; v.f = f;
  unsigned int x = v.i;
  return (unsigned short)((x + 0x7FFFu + ((x >> 16) & 1u)) >> 16);
}

// ---------- dtype sniff
__global__ void k_sniff(const ushort_t* __restrict__ nf16,
                        const int* __restrict__ dsti, int* __restrict__ flags){
  __shared__ int cnt[2];
  int t = threadIdx.x;
  if (t < 2) cnt[t] = 0;
  __syncthreads();
  int bad = 0;
  for (int i = t; i < 1024; i += 256){
    unsigned short u = nf16[2*i];
    int e = (u >> 7) & 0xFF;
    if (e < 96 || e > 159) bad++;
  }
  if (bad) atomicAdd(&cnt[0], bad);
  if (t < 256 && dsti[2*t+1] == 0) atomicAdd(&cnt[1], 1);
  __syncthreads();
  if (t == 0){
    flags[0] = (cnt[0] > 300) ? 1 : 0;
    flags[1] = (cnt[1] > 250) ? 1 : 0;
  }
}

// ---------- batched canonicalization: 15 tensors in one dispatch
struct CanonArgs {
  const void* in[15];
  float* out[15];
  int n[15];
};
__global__ void k_canon_all(CanonArgs a, const int* __restrict__ flags){
  int j = blockIdx.y;
  int n = a.n[j];
  int fp32 = flags[0];
  const void* in = a.in[j];
  float* out = a.out[j];
  for (int i = blockIdx.x*256 + threadIdx.x; i < n; i += gridDim.x*256){
    if (fp32) out[i] = ((const float*)in)[i];
    else      out[i] = bsf(((const ushort_t*)in)[i]);
  }
}
__global__ void k_canoni(const void* __restrict__ in, int* __restrict__ out,
                         int n, const int* __restrict__ flags){
  int i = blockIdx.x*256 + threadIdx.x;
  if (i >= n) return;
  long long v = flags[1] ? ((const long long*)in)[i]
                         : (long long)((const int*)in)[i];
  int vi = (int)v;
  if (vi < 0) vi = 0;
  if (vi >= NN) vi = NN-1;
  out[i] = vi;
}

// ---------- one-time: h0 = relu(nf @ W_proj + b_proj) -> fp32 hid + ab h-parts
__global__ void k_proj(const float* __restrict__ nf, const float* __restrict__ Wp,
                       const float* __restrict__ bp, float* __restrict__ hid,
                       ushort_t* __restrict__ ab){
  __shared__ float nfl[4][DIN];
  int t = threadIdx.x, blk = blockIdx.x;
  for (int idx = t; idx < 4*DIN; idx += 256){
    int vl = idx / DIN, i = idx - vl*DIN;
    nfl[vl][i] = nf[(size_t)(blk*4+vl)*DIN + i];
  }
  __syncthreads();
  int vl = t >> 6, o = t & 63;
  int v = blk*4 + vl;
  float acc = bp[o];
  for (int i = 0; i < DIN; ++i) acc += nfl[vl][i] * Wp[i*DD + o];
  float r = fmaxf(acc, 0.f);
  hid[(size_t)v*DD + o] = r;
  ushort_t hh = fsb(r);
  float hl = r - bsf(hh);
  ab[(size_t)v*KAB + 64 + o]  = hh;        // h_hi
  ab[(size_t)v*KAB + 192 + o] = fsb(hl);   // h_lo
  ab[(size_t)v*KAB + 320 + o] = hh;        // h_hi copy (pairs W_lo)
}

// ---------- one-time: t = relu(ef @ W_e1 + b_e1), fp32
__global__ void k_emlp(const float* __restrict__ ef, const float* __restrict__ W1,
                       const float* __restrict__ b1, float* __restrict__ tfp){
  __shared__ float efl[2][DEIN];
  int t = threadIdx.x, blk = blockIdx.x;
  if (t < 2*DEIN){
    int el = t / DEIN, i = t - el*DEIN;
    efl[el][i] = ef[(size_t)(blk*2+el)*DEIN + i];
  }
  __syncthreads();
  int el = t >> 7, c = t & 127;
  float acc = b1[c];
  for (int i = 0; i < DEIN; ++i) acc += efl[el][i] * W1[i*EH + c];
  tfp[(size_t)(blk*2+el)*EH + c] = fmaxf(acc, 0.f);
}

// ---------- one-time: w2rtx rows permuted so G comes out o-major
__global__ void k_w2rtx(const float* __restrict__ W2, const float* __restrict__ b2,
                        ushort_t* __restrict__ w2rtx){
  int idx = blockIdx.x*256 + threadIdx.x;
  if (idx < NGX*DD){
    int n = idx >> 6, i = idx & 63;
    float v;
    if (n < NG){
      int o = n >> 7, k = n & 127;
      v = W2[(size_t)k*4096 + i*64 + o];
    } else {
      v = b2[i*64 + (n - NG)];
    }
    w2rtx[idx] = fsb(v);
  }
}

// ---------- one-time: GRU split weight matrix wg[c][k], c in [0,256), k in [0,384)
// A k-blocks: 0:m_hi 1:h_hi 2:m_lo 3:h_lo 4:m_hi(copy) 5:h_hi(copy)
// B rows:     W_hi    W_hi   W_hi   W_hi   W_lo        W_lo   (masked per gate)
__global__ void k_wgru(const float* __restrict__ Wih, const float* __restrict__ Whh,
                       ushort_t* __restrict__ wg){
  int pos = blockIdx.x*256 + threadIdx.x;
  if (pos >= 256*KAB) return;
  int c = pos / KAB, k = pos - c*KAB;
  int kb = k >> 6, i = k & 63;
  int g = c >> 6, o = c & 63;
  float w = 0.f;
  if ((kb & 1) == 0){          // m-side: Wih
    if (g == 0)      w = Wih[(size_t)(o)*64 + i];
    else if (g == 1) w = Wih[(size_t)(64+o)*64 + i];
    else if (g == 2) w = Wih[(size_t)(128+o)*64 + i];
  } else {                     // h-side: Whh
    if (g == 0)      w = Whh[(size_t)(o)*64 + i];
    else if (g == 1) w = Whh[(size_t)(64+o)*64 + i];
    else if (g == 3) w = Whh[(size_t)(128+o)*64 + i];
  }
  ushort_t hi = fsb(w);
  wg[pos] = (kb >= 4) ? fsb(w - bsf(hi)) : hi;
}

// ---------- CSR build (src only) + degree/invd for dst
__global__ void k_zero(int* __restrict__ p, int n){
  int i = blockIdx.x*256 + threadIdx.x;
  if (i < n) p[i] = 0;
}
__global__ void k_deg(const int* __restrict__ idxarr, int* __restrict__ deg){
  int e = blockIdx.x*256 + threadIdx.x;
  if (e < NE) atomicAdd(&deg[idxarr[e]], 1);
}
__global__ void k_invd(const int* __restrict__ deg, float* __restrict__ invd){
  int i = blockIdx.x*256 + threadIdx.x;
  if (i < NN){
    int d = deg[i];
    invd[i] = (d > 0) ? 1.0f/(float)d : 0.0f;
  }
}
__global__ void k_scan(const int* __restrict__ deg, int* __restrict__ rowp,
                       float* __restrict__ invd){
  __shared__ int ssum[256];
  int t = threadIdx.x;
  const int STRIP = (NN + 255) / 256;
  int lo = t*STRIP, hi = (lo + STRIP < NN) ? lo + STRIP : NN;
  int s = 0;
  for (int i = lo; i < hi; ++i) s += deg[i];
  ssum[t] = s;
  __syncthreads();
  if (t == 0){
    int acc = 0;
    for (int i = 0; i < 256; ++i){ int v = ssum[i]; ssum[i] = acc; acc += v; }
  }
  __syncthreads();
  int acc = ssum[t];
  for (int i = lo; i < hi; ++i){
    rowp[i] = acc;
    int d = deg[i];
    invd[i] = (d > 0) ? 1.0f/(float)d : 0.0f;
    acc += d;
  }
  if (t == 255) rowp[NN] = acc;
}
__global__ void k_scatter(const int* __restrict__ idxarr, const int* __restrict__ rowp,
                          int* __restrict__ cursor, int* __restrict__ eidx){
  int e = blockIdx.x*256 + threadIdx.x;
  if (e < NE){
    int d = idxarr[e];
    int pos = atomicAdd(&cursor[d], 1);
    eidx[rowp[d] + pos] = e;
  }
}

// ---------- prep: rst init to conv_bias (per-step re-init folded into gru_pre)
__global__ void k_rstinit(const float* __restrict__ cbias, float* __restrict__ rst){
  int i = blockIdx.x*256 + threadIdx.x;
  if (i < NN*DD) rst[i] = cbias[i & 63];
}

// ---------- per chunk: G[m][n'] = h_hi[chunk0+m] @ w2rtx  (bf16 MFMA, 128x64 tile)
__global__ __launch_bounds__(256) void k_ggemm(const ushort_t* __restrict__ ab,
        const ushort_t* __restrict__ w2rtx, ushort_t* __restrict__ G,
        int chunk0, int cact){
  __shared__ __align__(16) ushort_t As[128][72];  // 18.4 KB
  __shared__ __align__(16) ushort_t Bs[64][72];   //  9.2 KB
  int t = threadIdx.x;
  int n0 = blockIdx.x * 64;
  int m0 = blockIdx.y * 128;
  #pragma unroll
  for (int it = 0; it < 6; ++it){
    int cid = t + it*256;
    int r = cid >> 3, ko = (cid & 7) * 8;
    if (r < 128){
      int gm = chunk0 + m0 + r; if (gm >= NN) gm = NN-1;  // clamp; store guarded
      *(uint4*)&As[r][ko] = *(const uint4*)(ab + (size_t)gm*KAB + 64 + ko);
    } else {
      *(uint4*)&Bs[r-128][ko] = *(const uint4*)(w2rtx + (size_t)(n0 + r-128)*DD + ko);
    }
  }
  __syncthreads();
  int w = t >> 6, lane = t & 63;
  int lrow = lane & 15, quad = lane >> 4;
  float4v acc[2][4];
  #pragma unroll
  for (int mt = 0; mt < 2; ++mt)
    #pragma unroll
    for (int nt = 0; nt < 4; ++nt) acc[mt][nt] = (float4v){0.f,0.f,0.f,0.f};
  #pragma unroll
  for (int ks = 0; ks < 2; ++ks){
    short8v a0 = *(const short8v*)&As[w*32 + lrow][ks*32 + quad*8];
    short8v a1 = *(const short8v*)&As[w*32 + 16 + lrow][ks*32 + quad*8];
    #pragma unroll
    for (int nt = 0; nt < 4; ++nt){
      short8v b = *(const short8v*)&Bs[nt*16 + lrow][ks*32 + quad*8];
      acc[0][nt] = __builtin_amdgcn_mfma_f32_16x16x32_bf16(a0, b, acc[0][nt], 0, 0, 0);
      acc[1][nt] = __builtin_amdgcn_mfma_f32_16x16x32_bf16(a1, b, acc[1][nt], 0, 0, 0);
    }
  }
  #pragma unroll
  for (int mt = 0; mt < 2; ++mt){
    #pragma unroll
    for (int nt = 0; nt < 4; ++nt){
      int col = n0 + nt*16 + lrow;
      #pragma unroll
      for (int reg = 0; reg < 4; ++reg){
        int m = m0 + w*32 + mt*16 + quad*4 + reg;
        if (m < cact) G[(size_t)m*NGX + col] = fsb(acc[mt][nt][reg]);
      }
    }
  }
}

// ---------- per chunk: for each edge of node v: atomicAdd rst[dst] += inv*msg
__global__ __launch_bounds__(256) void k_edge(const float* __restrict__ tfp,
      const ushort_t* __restrict__ G,
      const int* __restrict__ rowp2, const int* __restrict__ eidx2,
      const int* __restrict__ dstc, const float* __restrict__ invd,
      float* __restrict__ rst, int chunk0){
  __shared__ __align__(16) ushort_t gl[NG];    // 16 KB, swizzled per-o chunks
  __shared__ __align__(16) ushort_t bhl[64];
  __shared__ __align__(16) float tl[4][128];   // 2 KB
  __shared__ int eids[4];
  int t = threadIdx.x;
  int vloc = blockIdx.x;
  int v = chunk0 + vloc;
  int b = rowp2[v], e_end = rowp2[v+1];
  if (b == e_end) return;                      // block-uniform
  const ushort_t* grow = G + (size_t)vloc*NGX;
  for (int idx = t; idx < 1032; idx += 256){   // 1032 uint4 = 8256 bf16, coalesced
    uint4 val = *(const uint4*)(grow + idx*8);
    if (idx < 1024){
      int o = idx >> 4, c = idx & 15;
      *(uint4*)&gl[o*128 + ((c ^ (o & 15)) << 3)] = val;
    } else {
      *(uint4*)&bhl[(idx - 1024)*8] = val;
    }
  }
  int w = t >> 6, o = t & 63;
  int sw = o & 15;
  const uint4* gv = (const uint4*)&gl[o*128];  // 16 swizzled chunks of 8 bf16
  for (int base = b; base < e_end; base += 4){
    __syncthreads();                           // also covers gl/bhl visibility
    if (t < 4){
      int ei = base + t;
      eids[t] = (ei < e_end) ? eidx2[ei] : -1;
    }
    __syncthreads();
    for (int idx = t; idx < 512; idx += 256){
      int slot = idx >> 7, k = idx & 127;
      int e = eids[slot];
      tl[slot][k] = (e >= 0) ? tfp[(size_t)e*EH + k] : 0.f;
    }
    __syncthreads();
    int e = eids[w];
    if (e >= 0){
      float acc = bsf(bhl[o]);
      #pragma unroll
      for (int c = 0; c < 16; ++c){
        uint4 g8 = gv[c ^ sw];
        float4 ta = *(const float4*)&tl[w][c*8];
        float4 tb = *(const float4*)&tl[w][c*8 + 4];
        acc += ta.x*blo(g8.x) + ta.y*bhi(g8.x) + ta.z*blo(g8.y) + ta.w*bhi(g8.y);
        acc += tb.x*blo(g8.z) + tb.y*bhi(g8.z) + tb.z*blo(g8.w) + tb.w*bhi(g8.w);
      }
      int d = dstc[e];
      atomicAdd(&rst[(size_t)d*DD + o], acc * invd[d]);
    }
  }
}

// ---------- per step: BN column partials over rst (dense)
__global__ void k_bnp(const float* __restrict__ rst, float* __restrict__ part){
  __shared__ float ls[256], ls2[256];
  int t = threadIdx.x, blk = blockIdx.x;
  int o = t & 63, gg = t >> 6;
  int r0 = blk*256;
  float s = 0.f, s2 = 0.f;
  for (int j = 0; j < 64; ++j){
    int r = r0 + gg + j*4;
    if (r < NN){
      float x = rst[(size_t)r*DD + o];
      s += x; s2 += x*x;
    }
  }
  ls[t] = s; ls2[t] = s2;
  __syncthreads();
  if (gg == 0){
    part[blk*128 + o]      = ls[o] + ls[64+o] + ls[128+o] + ls[192+o];
    part[blk*128 + 64 + o] = ls2[o] + ls2[64+o] + ls2[128+o] + ls2[192+o];
  }
}
__global__ void k_bnf(const float* __restrict__ part, float* __restrict__ stats){
  __shared__ float sh[128];
  int t = threadIdx.x;  // 128 threads
  float s = 0.f;
  for (int b = 0; b < NBN; ++b) s += part[b*128 + t];
  sh[t] = s;
  __syncthreads();
  if (t < 64){
    float mu = sh[t] / (float)NN;
    float var = sh[64+t] / (float)NN - mu*mu;
    if (var < 0.f) var = 0.f;
    stats[t] = mu;
    stats[64 + t] = rsqrtf(var + 1e-5f);
  }
}

// ---------- per step: m = relu(BN(rst)) -> split into ab; reset rst = cbias
__global__ void k_gru_pre(const float* __restrict__ rst, const float* __restrict__ stats,
      const float* __restrict__ gamma, const float* __restrict__ beta,
      const float* __restrict__ cbias,
      ushort_t* __restrict__ ab, float* __restrict__ rstw){
  int t = threadIdx.x, blk = blockIdx.x;
  int vl = t >> 6, o = t & 63;
  int v = blk*4 + vl;
  float x = rst[(size_t)v*DD + o];
  float m = fmaxf((x - stats[o])*stats[64+o]*gamma[o] + beta[o], 0.f);
  ushort_t mh = fsb(m);
  float mlo = m - bsf(mh);
  ab[(size_t)v*KAB + o]       = mh;         // m_hi
  ab[(size_t)v*KAB + 128 + o] = fsb(mlo);   // m_lo
  ab[(size_t)v*KAB + 256 + o] = mh;         // m_hi copy (pairs W_lo)
  rstw[(size_t)v*DD + o] = cbias[o];        // re-init accumulator for next step
}

// ---------- per step: gbuf[v][c] = ab[v] @ wg^T  (MFMA, 128x64 tile, K=384)
__global__ __launch_bounds__(256) void k_gru_gemm(const ushort_t* __restrict__ ab,
        const ushort_t* __restrict__ wg, float* __restrict__ gbuf){
  __shared__ __align__(16) ushort_t As[128][136];  // 34.8 KB
  __shared__ __align__(16) ushort_t Bs[64][136];   // 17.4 KB
  int t = threadIdx.x;
  int n0 = blockIdx.x * 64;
  int m0 = blockIdx.y * 128;
  int w = t >> 6, lane = t & 63;
  int lrow = lane & 15, quad = lane >> 4;
  float4v acc[2][4];
  #pragma unroll
  for (int mt = 0; mt < 2; ++mt)
    #pragma unroll
    for (int nt = 0; nt < 4; ++nt) acc[mt][nt] = (float4v){0.f,0.f,0.f,0.f};
  for (int kt = 0; kt < 3; ++kt){
    __syncthreads();
    #pragma unroll
    for (int it = 0; it < 8; ++it){      // As: 128 rows x 16 chunks of 8
      int cid = t + it*256;
      int r = cid >> 4, ko = (cid & 15) * 8;
      int gm = m0 + r; if (gm >= NN) gm = NN-1;
      *(uint4*)&As[r][ko] = *(const uint4*)(ab + (size_t)gm*KAB + kt*128 + ko);
    }
    #pragma unroll
    for (int it = 0; it < 4; ++it){      // Bs: 64 rows x 16 chunks of 8
      int cid = t + it*256;
      int r = cid >> 4, ko = (cid & 15) * 8;
      *(uint4*)&Bs[r][ko] = *(const uint4*)(wg + (size_t)(n0 + r)*KAB + kt*128 + ko);
    }
    __syncthreads();
    #pragma unroll
    for (int ks = 0; ks < 4; ++ks){
      short8v a0 = *(const short8v*)&As[w*32 + lrow][ks*32 + quad*8];
      short8v a1 = *(const short8v*)&As[w*32 + 16 + lrow][ks*32 + quad*8];
      #pragma unroll
      for (int nt = 0; nt < 4; ++nt){
        short8v b = *(const short8v*)&Bs[nt*16 + lrow][ks*32 + quad*8];
        acc[0][nt] = __builtin_amdgcn_mfma_f32_16x16x32_bf16(a0, b, acc[0][nt], 0, 0, 0);
        acc[1][nt] = __builtin_amdgcn_mfma_f32_16x16x32_bf16(a1, b, acc[1][nt], 0, 0, 0);
      }
    }
  }
  #pragma unroll
  for (int mt = 0; mt < 2; ++mt){
    #pragma unroll
    for (int nt = 0; nt < 4; ++nt){
      int col = n0 + nt*16 + lrow;
      #pragma unroll
      for (int reg = 0; reg < 4; ++reg){
        int m = m0 + w*32 + mt*16 + quad*4 + reg;
        if (m < NN) gbuf[(size_t)m*256 + col] = acc[mt][nt][reg];
      }
    }
  }
}

// ---------- per step: gates + h update; maintain ab h-parts and fp32 hid
__global__ void k_gru_fin(const float* __restrict__ gbuf,
      const float* __restrict__ bih, const float* __restrict__ bhh,
      float* __restrict__ hid, ushort_t* __restrict__ ab,
      float* __restrict__ out, int write_out){
  int t = threadIdx.x, blk = blockIdx.x;
  int vl = t >> 6, o = t & 63;
  int v = blk*4 + vl;
  const float* gb = gbuf + (size_t)v*256;
  float aR  = gb[o]       + bih[o]      + bhh[o];
  float aZ  = gb[64 + o]  + bih[64+o]   + bhh[64+o];
  float aNi = gb[128 + o] + bih[128+o];
  float aNh = gb[192 + o] + bhh[128+o];
  float hprev = hid[(size_t)v*DD + o];
  float r = 1.f/(1.f+__expf(-aR));
  float z = 1.f/(1.f+__expf(-aZ));
  float n = tanhf(aNi + r*aNh);
  float hnew = (1.f - z)*n + z*hprev;
  hid[(size_t)v*DD + o] = hnew;
  ushort_t hh = fsb(hnew);
  float hl = hnew - bsf(hh);
  ab[(size_t)v*KAB + 64 + o]  = hh;
  ab[(size_t)v*KAB + 192 + o] = fsb(hl);
  ab[(size_t)v*KAB + 320 + o] = hh;
  if (write_out) out[(size_t)v*DD + o] = hnew;
}

extern "C" void kernel_launch(void* const* d_in, const int* in_sizes, int n_in,
                              void* d_out, int out_size, void* d_ws, size_t ws_size,
                              hipStream_t stream){
  (void)out_size;
  float* out = (float*)d_out;

  // resolve input positions by size (== dict order on this instance)
  int p_nf=-1,p_ef=-1,p_src=-1,p_dst=-1,p_Wp=-1,p_bp=-1,p_W1=-1,p_b1=-1,
      p_W2=-1,p_b2=-1,p_cb=-1,p_gam=-1,p_bet=-1,p_Wih=-1,p_Whh=-1,p_bih=-1,p_bhh=-1;
  int c60000=0,c64=0,c12288=0,c192=0;
  for (int i = 0; i < n_in; ++i){
    switch (in_sizes[i]){
      case 1110000: p_nf = i; break;
      case 720000:  p_ef = i; break;
      case 60000:   if (c60000++ == 0) p_src = i; else p_dst = i; break;
      case 4736:    p_Wp = i; break;
      case 64:      { if (c64==0) p_bp=i; else if (c64==1) p_cb=i;
                      else if (c64==2) p_gam=i; else p_bet=i; c64++; } break;
      case 1536:    p_W1 = i; break;
      case 128:     p_b1 = i; break;
      case 524288:  p_W2 = i; break;
      case 4096:    p_b2 = i; break;
      case 12288:   if (c12288++ == 0) p_Wih = i; else p_Whh = i; break;
      case 192:     if (c192++ == 0) p_bih = i; else p_bhh = i; break;
      default: break;
    }
  }

  char* p = (char*)d_ws;
  auto alloc = [&](size_t bytes)->char*{
    char* r = p; p += (bytes + 255) & ~(size_t)255; return r;
  };
  int* flags = (int*)alloc(256);
  const int FPOS[15] = {p_nf,p_ef,p_Wp,p_bp,p_W1,p_b1,p_W2,p_b2,p_cb,p_gam,p_bet,
                        p_Wih,p_Whh,p_bih,p_bhh};
  CanonArgs ca;
  int maxn = 0;
  for (int j = 0; j < 15; ++j){
    int n = in_sizes[FPOS[j]];
    ca.in[j]  = d_in[FPOS[j]];
    ca.out[j] = (float*)alloc((size_t)n * 4);
    ca.n[j]   = n;
    if (n > maxn) maxn = n;
  }
  const float* nf  = ca.out[0];  const float* ef  = ca.out[1];
  const float* Wp  = ca.out[2];  const float* bp  = ca.out[3];
  const float* W1  = ca.out[4];  const float* b1  = ca.out[5];
  const float* W2  = ca.out[6];  const float* b2  = ca.out[7];
  const float* cb  = ca.out[8];  const float* gam = ca.out[9];
  const float* bet = ca.out[10]; const float* Wih = ca.out[11];
  const float* Whh = ca.out[12]; const float* bih = ca.out[13];
  const float* bhh = ca.out[14];
  int* srcc = (int*)alloc((size_t)NE*4);
  int* dstc = (int*)alloc((size_t)NE*4);

  float* tfp      = (float*)alloc((size_t)NE*EH*4);      // 30.7 MB
  ushort_t* w2rtx = (ushort_t*)alloc((size_t)NGX*DD*2);  // 1.06 MB
  float* hid      = (float*)alloc((size_t)NN*DD*4);
  ushort_t* ab    = (ushort_t*)alloc((size_t)NN*KAB*2);  // 11.5 MB split activations
  ushort_t* wg    = (ushort_t*)alloc((size_t)256*KAB*2); // 0.2 MB split GRU weights
  float* gbuf     = (float*)alloc((size_t)NN*256*4);     // 15.4 MB gate pre-acts
  float* rst      = (float*)alloc((size_t)NN*DD*4);
  float* part     = (float*)alloc((size_t)NBN*128*4);
  float* stats    = (float*)alloc(128*4);
  int* degall     = (int*)alloc((size_t)4*NN*4);
  int* deg  = degall;        // dst degrees (for invd)
  int* deg2 = degall + 2*NN; int* cursor2 = degall + 3*NN;
  float* invd = (float*)alloc((size_t)NN*4);
  int* rowp2  = (int*)alloc((size_t)(NN+1)*4);
  float* invd2= (float*)alloc((size_t)NN*4);
  int* eidx2  = (int*)alloc((size_t)NE*4);

  // adaptive bf16 G-chunk (deterministic per ws_size); L3-resident cap
  size_t used = (size_t)(p - (char*)d_ws);
  size_t rem = (ws_size > used) ? (ws_size - used) : 0;
  long long Cll = (long long)(rem / ((size_t)NGX*2));
  int C = (Cll > 7552) ? 7552 : (int)Cll;
  C &= ~127;                  // multiple of 128 (ggemm m-tile)
  if (C < 128)  C = 128;
  ushort_t* G = (ushort_t*)alloc((size_t)C*NGX*2);
  int nch = (NN + C - 1) / C;

  k_sniff<<<1, 256, 0, stream>>>((const ushort_t*)d_in[p_nf], (const int*)d_in[p_dst], flags);
  k_canon_all<<<dim3((maxn+255)/256, 15), 256, 0, stream>>>(ca, flags);
  k_canoni<<<(NE+255)/256, 256, 0, stream>>>(d_in[p_src], srcc, NE, flags);
  k_canoni<<<(NE+255)/256, 256, 0, stream>>>(d_in[p_dst], dstc, NE, flags);

  k_proj <<<NN/4,  256, 0, stream>>>(nf, Wp, bp, hid, ab);
  k_emlp <<<NE/2,  256, 0, stream>>>(ef, W1, b1, tfp);
  k_w2rtx<<<(NGX*DD+255)/256, 256, 0, stream>>>(W2, b2, w2rtx);
  k_wgru <<<(256*KAB+255)/256, 256, 0, stream>>>(Wih, Whh, wg);
  k_zero <<<(4*NN+255)/256, 256, 0, stream>>>(degall, 4*NN);
  k_deg  <<<(NE+255)/256, 256, 0, stream>>>(dstc, deg);
  k_deg  <<<(NE+255)/256, 256, 0, stream>>>(srcc, deg2);
  k_invd <<<(NN+255)/256, 256, 0, stream>>>(deg, invd);
  k_scan <<<1, 256, 0, stream>>>(deg2, rowp2, invd2);
  k_scatter<<<(NE+255)/256, 256, 0, stream>>>(srcc, rowp2, cursor2, eidx2);
  k_rstinit<<<(NN*DD+255)/256, 256, 0, stream>>>(cb, rst);

  for (int s = 0; s < NSTEPS; ++s){
    for (int c = 0; c < nch; ++c){
      int chunk0 = c*C;
      int cact = (NN - chunk0 < C) ? (NN - chunk0) : C;
      k_ggemm<<<dim3(NGX/64, (cact+127)/128), 256, 0, stream>>>(ab, w2rtx, G, chunk0, cact);
      k_edge <<<cact, 256, 0, stream>>>(tfp, G, rowp2, eidx2, dstc, invd, rst, chunk0);
    }
    k_bnp <<<NBN, 256, 0, stream>>>(rst, part);
    k_bnf <<<1, 128, 0, stream>>>(part, stats);
    k_gru_pre <<<NN/4, 256, 0, stream>>>(rst, stats, gam, bet, cb, ab, rst);
    k_gru_gemm<<<dim3(4, (NN+127)/128), 256, 0, stream>>>(ab, wg, gbuf);
    k_gru_fin <<<NN/4, 256, 0, stream>>>(gbuf, bih, bhh, hid, ab, out,
                                         (s == NSTEPS-1) ? 1 : 0);
  }
}